// Round 1
// baseline (3982.372 us; speedup 1.0000x reference)
//
#include <hip/hip_runtime.h>
#include <cstdio>

// ---------------------------------------------------------------------------
// Round 4: latency pipelining of the two big MFMA kernels.
//  - gemm_node: register-prefetch segment k+1's A-tile during segment k's
//    MFMA phase (stage latency overlapped; 2 of 3 HBM round-trips hidden).
//  - gemm_qual: edge metadata hoisted to index phase; x[src] restage gather
//    issued into registers concurrently with the compose gather (two random
//    HBM round-trips overlap; 5 barriers -> 4).
// Everything else unchanged from round 3.
// ---------------------------------------------------------------------------

#define ALPHA_MIX 0.8f

constexpr int N_ENT  = 200000;
constexpr int D_     = 200;
constexpr int E_DIR_ = 500000;
constexpr int NQ_    = 400000;
constexpr int B_     = 4096;

constexpr int NT_  = 13;   // 13 column tiles of 16 (208 padded, 200 used)
constexpr int LDA_ = 232;  // LDS A row stride in bf16 elements
constexpr int WLD_ = 224;  // Bp row stride = padded K

constexpr size_t OFS_SUB  = 0;
constexpr size_t OFS_REL  = 819200;
constexpr size_t OFS_QOBJ = 1638400;
constexpr size_t OFS_QREL = 6553600;
constexpr size_t OFS_X    = 11468800;
constexpr size_t OFS_R    = 51468800;

typedef __bf16 bf16x8 __attribute__((ext_vector_type(8)));
typedef float  f32x4  __attribute__((ext_vector_type(4)));

__device__ __forceinline__ unsigned int f2bf(float f) {
  unsigned int u = __float_as_uint(f);
  u += 0x7FFFu + ((u >> 16) & 1u);   // RNE
  return u >> 16;
}
__device__ __forceinline__ unsigned long long pack4bf(float x, float y, float z, float w) {
  return (unsigned long long)f2bf(x) | ((unsigned long long)f2bf(y) << 16) |
         ((unsigned long long)f2bf(z) << 32) | ((unsigned long long)f2bf(w) << 48);
}
__device__ __forceinline__ float bf_lo(unsigned int u) { return __uint_as_float(u << 16); }
__device__ __forceinline__ float bf_hi(unsigned int u) { return __uint_as_float(u & 0xFFFF0000u); }
__device__ __forceinline__ unsigned int mulpk(unsigned int a, unsigned int b) {
  return f2bf(bf_lo(a) * bf_lo(b)) | (f2bf(bf_hi(a) * bf_hi(b)) << 16);
}

typedef short v2s __attribute__((ext_vector_type(2)));
__device__ __forceinline__ void atomic_pk_add_bf16(unsigned short* addr, unsigned int pk) {
#if __has_builtin(__builtin_amdgcn_global_atomic_fadd_v2bf16)
  v2s v;
  __builtin_memcpy(&v, &pk, 4);
  __builtin_amdgcn_global_atomic_fadd_v2bf16(
      (__attribute__((address_space(1))) v2s*)(unsigned long long)addr, v);
#else
  unsigned int* ap = (unsigned int*)addr;
  unsigned int old = *ap;
  while (true) {
    unsigned int nv = f2bf(bf_lo(old) + bf_lo(pk)) | (f2bf(bf_hi(old) + bf_hi(pk)) << 16);
    unsigned int prev = atomicCAS(ap, old, nv);
    if (prev == old) break;
    old = prev;
  }
#endif
}

// ---------------------------------------------------------------------------
// Qual GEMM: rows = quals. A[row] = x_bf[q_e]*rall_bf[q_r]; y = A@w_q.
// Epilogue: pre[dst[eid]] += 0.2*norm[eid] * x_bf[src[eid]] * y   (pk atomics)
// x[src] restage gather is issued into registers BEFORE the MFMA phase so
// its HBM round-trip overlaps the compose gather + MFMA.
// ---------------------------------------------------------------------------
__global__ __launch_bounds__(256)
void gemm_qual(const unsigned short* __restrict__ Xbf, const unsigned short* __restrict__ Rbf,
               const int* __restrict__ q_e, const int* __restrict__ q_r,
               const int* __restrict__ q_eid,
               const int* __restrict__ srcv, const int* __restrict__ dstv,
               const float* __restrict__ nrm,
               const unsigned short* __restrict__ Bp,
               unsigned short* __restrict__ pre, int nrows)
{
  __shared__ __align__(16) unsigned short As[64 * LDA_];
  __shared__ int s_g[64], s_r[64], s_src[64], s_dst[64];
  __shared__ float s_nm[64];

  const int t  = threadIdx.x;
  const int r0 = blockIdx.x * 64;

  // index + edge metadata phase (one dependent-gather chain, up front)
  if (t < 64) {
    int cr = min(r0 + t, nrows - 1);
    s_g[t] = q_e[cr]; s_r[t] = q_r[cr];
    int e = q_eid[cr];
    s_dst[t] = dstv[e];
    s_src[t] = srcv[e];
    s_nm[t]  = (1.0f - ALPHA_MIX) * nrm[e];
  }

  // staging task decomposition: 64 rows x 25 uint4 = 1600 tasks over 256 thr
  int ti[7], tc[7];
  #pragma unroll
  for (int j = 0; j < 7; j++) {
    if (j < 6 || t < 64) {
      int task = t + j * 256;
      ti[j] = task / 25; tc[j] = task % 25;
    }
  }

  __syncthreads();

  // issue x[src] restage gather into registers (overlaps everything below)
  uint4 rx[7];
  #pragma unroll
  for (int j = 0; j < 7; j++)
    if (j < 6 || t < 64)
      rx[j] = ((const uint4*)(Xbf + (size_t)s_src[ti[j]] * D_))[tc[j]];

  // compose A = x[q_e] * rall[q_r] into LDS
  #pragma unroll
  for (int j = 0; j < 7; j++) {
    if (j < 6 || t < 64) {
      uint4 xv = ((const uint4*)(Xbf + (size_t)s_g[ti[j]] * D_))[tc[j]];
      uint4 rv = ((const uint4*)(Rbf + (size_t)s_r[ti[j]] * D_))[tc[j]];
      uint4 o;
      o.x = mulpk(xv.x, rv.x); o.y = mulpk(xv.y, rv.y);
      o.z = mulpk(xv.z, rv.z); o.w = mulpk(xv.w, rv.w);
      *(uint4*)(As + ti[j] * LDA_ + tc[j] * 8) = o;
    }
  }
  for (int task = t; task < 64 * 3; task += 256) {
    int i = task / 3, c = task % 3;
    *(uint4*)(As + i * LDA_ + 200 + c * 8) = make_uint4(0, 0, 0, 0);
  }
  __syncthreads();

  const int wave = t >> 6, lane = t & 63;
  const int m = lane & 15, quad = lane >> 4;

  f32x4 acc[NT_];
  const f32x4 zero = {0.f, 0.f, 0.f, 0.f};
  #pragma unroll
  for (int i = 0; i < NT_; i++) acc[i] = zero;

  {
    const unsigned short* arow = As + (wave * 16 + m) * LDA_ + quad * 8;
    const unsigned short* brow = Bp + (size_t)m * WLD_ + quad * 8;
    #pragma unroll
    for (int ks = 0; ks < 7; ks++) {
      bf16x8 av = *(const bf16x8*)(arow + ks * 32);
      #pragma unroll
      for (int tt = 0; tt < NT_; tt++) {
        bf16x8 bv = *(const bf16x8*)(brow + (size_t)tt * 16 * WLD_ + ks * 32);
        acc[tt] = __builtin_amdgcn_mfma_f32_16x16x32_bf16(av, bv, acc[tt], 0, 0, 0);
      }
    }
  }

  // restage LDS with the prefetched x[src] rows (no global latency here)
  __syncthreads();
  #pragma unroll
  for (int j = 0; j < 7; j++)
    if (j < 6 || t < 64)
      *(uint4*)(As + ti[j] * LDA_ + tc[j] * 8) = rx[j];
  __syncthreads();

  #pragma unroll
  for (int rg = 0; rg < 4; rg++) {
    int row = r0 + wave * 16 + quad * 4 + rg;
    bool valid = row < nrows;
    int li = row - r0;
    size_t orow = (size_t)s_dst[li] * D_;
    float nm = s_nm[li];
    #pragma unroll
    for (int tt = 0; tt < NT_; tt++) {
      int col = tt * 16 + m;
      float xv = (col < D_) ? __uint_as_float(((unsigned int)As[li * LDA_ + col]) << 16) : 0.0f;
      float v  = acc[tt][rg] * nm * xv;
      float vn = __shfl_xor(v, 1);
      if (valid && !(m & 1) && col < D_) {
        unsigned int pk = f2bf(v) | (f2bf(vn) << 16);
        atomic_pk_add_bf16(pre + orow + col, pk);
      }
    }
  }
}

// ---------------------------------------------------------------------------
// CSR-based node gather: pre[d] = 0.8 * sum_{e in(d)} norm*x[src]*rall[et]
// one wave per node, fp32 accumulation, plain bf16 write.
// ---------------------------------------------------------------------------
__global__ __launch_bounds__(256)
void node_gather(const int* __restrict__ starts, const int* __restrict__ csr,
                 const int* __restrict__ srcv, const int* __restrict__ et,
                 const float* __restrict__ nrm,
                 const unsigned short* __restrict__ xbf,
                 const unsigned short* __restrict__ rallbf,
                 unsigned short* __restrict__ pre)
{
  int node = blockIdx.x * 4 + (threadIdx.x >> 6);
  if (node >= N_ENT) return;
  int lane = threadIdx.x & 63;
  int p0 = starts[node], p1 = starts[node + 1];
  float a0 = 0.f, a1 = 0.f, a2 = 0.f, a3 = 0.f;
  for (int p = p0; p < p1; p++) {
    int e = csr[p];
    int s = srcv[e], ty = et[e];
    float nm = nrm[e];
    if (lane < 50) {
      uint2 xv = ((const uint2*)(xbf + (size_t)s * D_))[lane];
      uint2 rv = ((const uint2*)(rallbf + (size_t)ty * D_))[lane];
      a0 += nm * bf_lo(xv.x) * bf_lo(rv.x);
      a1 += nm * bf_hi(xv.x) * bf_hi(rv.x);
      a2 += nm * bf_lo(xv.y) * bf_lo(rv.y);
      a3 += nm * bf_hi(xv.y) * bf_hi(rv.y);
    }
  }
  if (lane < 50) {
    uint2 o;
    o.x = f2bf(a0 * ALPHA_MIX) | (f2bf(a1 * ALPHA_MIX) << 16);
    o.y = f2bf(a2 * ALPHA_MIX) | (f2bf(a3 * ALPHA_MIX) << 16);
    ((uint2*)(pre + (size_t)node * D_))[lane] = o;
  }
}

// ---------------------------------------------------------------------------
// Node GEMM: 3 K-segments (pre_in, pre_out, x*loop_rel); /3 + bias + tanh.
// Software-pipelined: segment k+1's A-tile is prefetched into registers
// while segment k's MFMAs run, so the global round-trip overlaps compute.
// ---------------------------------------------------------------------------
__global__ __launch_bounds__(256)
void gemm_node(const unsigned short* __restrict__ pre0,
               const unsigned short* __restrict__ pre1,
               const unsigned short* __restrict__ xbf,
               const unsigned short* __restrict__ lrel,
               const unsigned short* __restrict__ B0,
               const unsigned short* __restrict__ B1,
               const unsigned short* __restrict__ B2,
               const float* __restrict__ bias,
               float* __restrict__ xo, unsigned short* __restrict__ xbf_out,
               int nrows)
{
  __shared__ __align__(16) unsigned short As[64 * LDA_];
  const int t  = threadIdx.x;
  const int r0 = blockIdx.x * 64;

  // staging task decomposition: 64 rows x 25 uint4 = 1600 tasks over 256 thr
  int ti[7], tc[7];
  size_t trow[7];
  #pragma unroll
  for (int j = 0; j < 7; j++) {
    if (j < 6 || t < 64) {
      int task = t + j * 256;
      ti[j] = task / 25; tc[j] = task % 25;
      trow[j] = (size_t)min(r0 + ti[j], nrows - 1) * D_;
    }
  }

  // prefetch segment 0 (pre0) into registers
  uint4 rv[7];
  #pragma unroll
  for (int j = 0; j < 7; j++)
    if (j < 6 || t < 64) rv[j] = ((const uint4*)(pre0 + trow[j]))[tc[j]];

  // zero-pad K region [200,224) once
  for (int task = t; task < 64 * 3; task += 256) {
    int i = task / 3, c = task % 3;
    *(uint4*)(As + i * LDA_ + 200 + c * 8) = make_uint4(0, 0, 0, 0);
  }

  const int wave = t >> 6, lane = t & 63;
  const int m = lane & 15, quad = lane >> 4;

  f32x4 acc[NT_];
  const f32x4 zero = {0.f, 0.f, 0.f, 0.f};
  #pragma unroll
  for (int i = 0; i < NT_; i++) acc[i] = zero;

  const unsigned short* Bsel[3] = {B0, B1, B2};

  #pragma unroll
  for (int seg = 0; seg < 3; seg++) {
    // drain prefetched registers into LDS (apply loop-rel compose on seg 2)
    #pragma unroll
    for (int j = 0; j < 7; j++) {
      if (j < 6 || t < 64) {
        uint4 vv = rv[j];
        if (seg == 2) {
          uint4 lv = ((const uint4*)lrel)[tc[j]];
          vv.x = mulpk(vv.x, lv.x); vv.y = mulpk(vv.y, lv.y);
          vv.z = mulpk(vv.z, lv.z); vv.w = mulpk(vv.w, lv.w);
        }
        *(uint4*)(As + ti[j] * LDA_ + tc[j] * 8) = vv;
      }
    }
    __syncthreads();

    // issue next segment's loads; they complete under the MFMA phase below
    if (seg == 0) {
      #pragma unroll
      for (int j = 0; j < 7; j++)
        if (j < 6 || t < 64) rv[j] = ((const uint4*)(pre1 + trow[j]))[tc[j]];
    } else if (seg == 1) {
      #pragma unroll
      for (int j = 0; j < 7; j++)
        if (j < 6 || t < 64) rv[j] = ((const uint4*)(xbf + trow[j]))[tc[j]];
    }
    __builtin_amdgcn_sched_barrier(0);   // keep prefetch issue above the MFMAs

    const unsigned short* arow = As + (wave * 16 + m) * LDA_ + quad * 8;
    const unsigned short* brow = Bsel[seg] + (size_t)m * WLD_ + quad * 8;
    #pragma unroll
    for (int ks = 0; ks < 7; ks++) {
      bf16x8 av = *(const bf16x8*)(arow + ks * 32);
      #pragma unroll
      for (int tt = 0; tt < NT_; tt++) {
        bf16x8 bv = *(const bf16x8*)(brow + (size_t)tt * 16 * WLD_ + ks * 32);
        acc[tt] = __builtin_amdgcn_mfma_f32_16x16x32_bf16(av, bv, acc[tt], 0, 0, 0);
      }
    }
    __syncthreads();
  }

  #pragma unroll
  for (int rg = 0; rg < 4; rg++) {
    int row = r0 + wave * 16 + quad * 4 + rg;
    if (row < nrows) {
      #pragma unroll
      for (int tt = 0; tt < NT_; tt++) {
        int col = tt * 16 + m;
        if (col < D_) {
          float v = acc[tt][rg] * (1.0f / 3.0f) + bias[col];
          float th = tanhf(v);
          if (xo) xo[(size_t)row * D_ + col] = th;
          xbf_out[(size_t)row * D_ + col] = (unsigned short)f2bf(th);
        }
      }
    }
  }
}

// ---------------------------------------------------------------------------
__global__ __launch_bounds__(256)
void gemm_rel200(const float* __restrict__ X, const unsigned short* __restrict__ Bp,
                 float* __restrict__ Out, int nrows)
{
  __shared__ __align__(16) unsigned short As[64 * LDA_];
  const int t  = threadIdx.x;
  const int r0 = blockIdx.x * 64;

  for (int task = t; task < 64 * 50; task += 256) {
    int i = task / 50, c = task % 50;
    int cr = min(r0 + i, nrows - 1);
    float4 xv = ((const float4*)(X + (size_t)cr * D_))[c];
    *(unsigned long long*)&As[i * LDA_ + c * 4] = pack4bf(xv.x, xv.y, xv.z, xv.w);
  }
  for (int task = t; task < 64 * 6; task += 256) {
    int i = task / 6, c = task % 6;
    *(unsigned long long*)&As[i * LDA_ + 200 + c * 4] = 0ull;
  }
  __syncthreads();

  const int wave = t >> 6, lane = t & 63;
  const int m = lane & 15, quad = lane >> 4;

  f32x4 acc[NT_];
  const f32x4 zero = {0.f, 0.f, 0.f, 0.f};
  #pragma unroll
  for (int i = 0; i < NT_; i++) acc[i] = zero;

  const unsigned short* arow = As + (wave * 16 + m) * LDA_ + quad * 8;
  const unsigned short* brow = Bp + (size_t)m * WLD_ + quad * 8;
  #pragma unroll
  for (int ks = 0; ks < 7; ks++) {
    bf16x8 av = *(const bf16x8*)(arow + ks * 32);
    #pragma unroll
    for (int tt = 0; tt < NT_; tt++) {
      bf16x8 bv = *(const bf16x8*)(brow + (size_t)tt * 16 * WLD_ + ks * 32);
      acc[tt] = __builtin_amdgcn_mfma_f32_16x16x32_bf16(av, bv, acc[tt], 0, 0, 0);
    }
  }

  #pragma unroll
  for (int rg = 0; rg < 4; rg++) {
    int row = r0 + wave * 16 + quad * 4 + rg;
    if (row < nrows) {
      #pragma unroll
      for (int tt = 0; tt < NT_; tt++) {
        int col = tt * 16 + m;
        if (col < D_) Out[(size_t)row * D_ + col] = acc[tt][rg];
      }
    }
  }
}

// ---------------------------------------------------------------------------
struct WP10 { const float* p[10]; };

__global__ void convert_weights(WP10 wp, unsigned short* __restrict__ wbp) {
  int i = blockIdx.x * 256 + threadIdx.x;
  if (i < 10 * 208 * WLD_) {
    int j = i / (208 * WLD_);
    int rem = i % (208 * WLD_);
    int n = rem / WLD_, k = rem % WLD_;
    float v = (n < D_ && k < D_) ? wp.p[j][(size_t)k * D_ + n] : 0.0f;  // Bp[n][k]=w[k][n]
    wbp[i] = (unsigned short)f2bf(v);
  }
}

__global__ void conv_f32_bf16_vec(const float* __restrict__ src,
                                  unsigned short* __restrict__ dst, int n4) {
  int i = blockIdx.x * 256 + threadIdx.x;
  if (i < n4) {
    float4 v = ((const float4*)src)[i];
    uint2 o;
    o.x = f2bf(v.x) | (f2bf(v.y) << 16);
    o.y = f2bf(v.z) | (f2bf(v.w) << 16);
    ((uint2*)dst)[i] = o;
  }
}

__global__ void build_rall(const float* __restrict__ rel_embs,
                           const float* __restrict__ loop_rel,
                           float* __restrict__ rall) {
  int i = blockIdx.x * 256 + threadIdx.x;
  if (i < 201 * D_) rall[i] = (i < 200 * D_) ? rel_embs[i] : loop_rel[i - 200 * D_];
}

__global__ void copy_row(const float* __restrict__ src, float* __restrict__ dst, int n) {
  int i = blockIdx.x * 256 + threadIdx.x;
  if (i < n) dst[i] = src[i];
}

__global__ void deg_count(const int* __restrict__ src, int* __restrict__ deg, int E) {
  int e = blockIdx.x * 256 + threadIdx.x;
  if (e < E) atomicAdd(&deg[src[e]], 1);
}

__global__ void norm_build(const int* __restrict__ src, const int* __restrict__ dst,
                           const int* __restrict__ deg, float* __restrict__ nrm, int E) {
  int e = blockIdx.x * 256 + threadIdx.x;
  if (e < E) {
    int a = deg[src[e]], b = deg[dst[e]];
    float fa = (a > 0) ? rsqrtf((float)a) : 0.0f;
    float fb = (b > 0) ? rsqrtf((float)b) : 0.0f;
    nrm[e] = fa * fb;
  }
}

// ---- exclusive scan (3 kernels) + CSR fill -------------------------------
constexpr int SCHUNK = 2048;

__global__ void scan_partial(const int* __restrict__ in, int* __restrict__ part, int n) {
  __shared__ int red[256];
  int b = blockIdx.x, t = threadIdx.x;
  int base = b * SCHUNK + t * 8;
  int s = 0;
  #pragma unroll
  for (int j = 0; j < 8; j++) { int i = base + j; if (i < n) s += in[i]; }
  red[t] = s; __syncthreads();
  for (int off = 128; off > 0; off >>= 1) {
    if (t < off) red[t] += red[t + off];
    __syncthreads();
  }
  if (t == 0) part[b] = red[0];
}

__global__ void scan_part_seq(int* part, int nb) {
  if (threadIdx.x == 0 && blockIdx.x == 0) {
    int run = 0;
    for (int i = 0; i < nb; i++) { int v = part[i]; part[i] = run; run += v; }
  }
}

__global__ void scan_final(const int* __restrict__ in, const int* __restrict__ part,
                           int* __restrict__ outs, int* __restrict__ cursor,
                           int n, int total) {
  __shared__ int buf[256];
  int b = blockIdx.x, t = threadIdx.x;
  int base = b * SCHUNK + t * 8;
  int v[8]; int s = 0;
  #pragma unroll
  for (int j = 0; j < 8; j++) { int i = base + j; v[j] = (i < n) ? in[i] : 0; s += v[j]; }
  buf[t] = s; __syncthreads();
  for (int off = 1; off < 256; off <<= 1) {
    int add = (t >= off) ? buf[t - off] : 0;
    __syncthreads();
    buf[t] += add;
    __syncthreads();
  }
  int excl = buf[t] - s + part[b];
  #pragma unroll
  for (int j = 0; j < 8; j++) {
    int i = base + j;
    if (i < n) { outs[i] = excl; cursor[i] = excl; }
    excl += v[j];
  }
  if (b == 0 && t == 0) outs[n] = total;
}

__global__ void fill_csr(const int* __restrict__ dstv, int* __restrict__ cursor,
                         int* __restrict__ csr, int E) {
  int e = blockIdx.x * 256 + threadIdx.x;
  if (e < E) {
    int pos = atomicAdd(&cursor[dstv[e]], 1);
    csr[pos] = e;
  }
}

__global__ void gather_out(const float* __restrict__ x2, const float* __restrict__ r2,
                           const int* __restrict__ ent_ix, const int* __restrict__ rel_ix,
                           const int* __restrict__ quals_ix, float* __restrict__ out) {
  int i = blockIdx.x * 256 + threadIdx.x;
  if (i >= B_ * 14 * 50) return;
  int b = i / 700, rem = i % 700, slot = rem / 50, c = rem % 50;
  const float* srcrow; float* dstrow;
  if (slot == 0)      { srcrow = x2 + (size_t)ent_ix[b] * D_;  dstrow = out + OFS_SUB + (size_t)b * D_; }
  else if (slot == 1) { srcrow = r2 + (size_t)rel_ix[b] * D_;  dstrow = out + OFS_REL + (size_t)b * D_; }
  else if (slot < 8)  { int j = slot - 2;
                        srcrow = x2 + (size_t)quals_ix[b * 12 + 2 * j + 1] * D_;
                        dstrow = out + OFS_QOBJ + ((size_t)b * 6 + j) * D_; }
  else                { int j = slot - 8;
                        srcrow = r2 + (size_t)quals_ix[b * 12 + 2 * j] * D_;
                        dstrow = out + OFS_QREL + ((size_t)b * 6 + j) * D_; }
  ((float4*)dstrow)[c] = ((const float4*)srcrow)[c];
}

// ---------------------------------------------------------------------------
extern "C" void kernel_launch(void* const* d_in, const int* in_sizes, int n_in,
                              void* d_out, int out_size, void* d_ws, size_t ws_size,
                              hipStream_t stream)
{
  const float* ent       = (const float*)d_in[0];
  const float* rel_embs  = (const float*)d_in[1];
  const float* loop_rel1 = (const float*)d_in[12];
  const float* loop_rel2 = (const float*)d_in[13];
  const float* b1        = (const float*)d_in[14];
  const float* b2        = (const float*)d_in[15];
  const int*   ei        = (const int*)d_in[16];
  const int*   etype     = (const int*)d_in[17];
  const int*   quals     = (const int*)d_in[18];
  const int*   ent_ix    = (const int*)d_in[19];
  const int*   rel_ix    = (const int*)d_in[20];
  const int*   quals_ix  = (const int*)d_in[21];

  char* wsb = (char*)d_ws;
  size_t off = 0;
  auto walloc = [&](size_t bytes) -> char* {
    char* p = wsb + off; off += (bytes + 511) & ~(size_t)511; return p;
  };
  unsigned short* pre0  = (unsigned short*)walloc((size_t)N_ENT * D_ * 2);   // 80 MB
  unsigned short* pre1  = (unsigned short*)walloc((size_t)N_ENT * D_ * 2);   // 80 MB
  unsigned short* x_bf  = (unsigned short*)walloc((size_t)N_ENT * D_ * 2);   // 80 MB
  float* norm1 = (float*)walloc((size_t)E_DIR_ * 4);
  float* norm2 = (float*)walloc((size_t)E_DIR_ * 4);
  int*   degA  = (int*)walloc((size_t)N_ENT * 4);   // counts of orig src
  int*   degB  = (int*)walloc((size_t)N_ENT * 4);   // counts of orig dst
  int*   starts0 = (int*)walloc((size_t)(N_ENT + 1) * 4);
  int*   starts1 = (int*)walloc((size_t)(N_ENT + 1) * 4);
  int*   cursor0 = (int*)walloc((size_t)N_ENT * 4);
  int*   cursor1 = (int*)walloc((size_t)N_ENT * 4);
  int*   csr0    = (int*)walloc((size_t)E_DIR_ * 4);
  int*   csr1    = (int*)walloc((size_t)E_DIR_ * 4);
  int*   part    = (int*)walloc((size_t)256 * 4);
  float* rall1 = (float*)walloc((size_t)201 * D_ * 4);
  float* rall2 = (float*)walloc((size_t)201 * D_ * 4);
  unsigned short* rall1_bf = (unsigned short*)walloc((size_t)201 * D_ * 2);
  unsigned short* rall2_bf = (unsigned short*)walloc((size_t)201 * D_ * 2);
  unsigned short* lrel1_bf = (unsigned short*)walloc((size_t)D_ * 2);
  unsigned short* lrel2_bf = (unsigned short*)walloc((size_t)D_ * 2);
  unsigned short* wbp = (unsigned short*)walloc((size_t)10 * 208 * WLD_ * 2);
  if (off > ws_size) fprintf(stderr, "ws overflow: need %zu have %zu\n", off, ws_size);

  float* out   = (float*)d_out;
  float* x_out = out + OFS_X;
  float* r_out = out + OFS_R;

  auto WB = [&](int j) { return wbp + (size_t)j * 208 * WLD_; };

  WP10 wp; for (int j = 0; j < 10; j++) wp.p[j] = (const float*)d_in[2 + j];
  convert_weights<<<(10 * 208 * WLD_ + 255) / 256, 256, 0, stream>>>(wp, wbp);
  build_rall<<<(201 * D_ + 255) / 256, 256, 0, stream>>>(rel_embs, loop_rel1, rall1);
  conv_f32_bf16_vec<<<(201 * 50 + 255) / 256, 256, 0, stream>>>(rall1, rall1_bf, 201 * 50);
  conv_f32_bf16_vec<<<(N_ENT * 50 + 255) / 256, 256, 0, stream>>>(ent, x_bf, N_ENT * 50);
  conv_f32_bf16_vec<<<1, 256, 0, stream>>>(loop_rel1, lrel1_bf, 50);
  conv_f32_bf16_vec<<<1, 256, 0, stream>>>(loop_rel2, lrel2_bf, 50);

  const int* src1 = ei;                // dir0 src = orig src
  const int* dst1 = ei + 2 * E_DIR_;   // dir0 dst = orig dst
  const int* src2 = ei + E_DIR_;       // dir1 src = orig dst
  const int* dst2 = ei + 3 * E_DIR_;   // dir1 dst = orig src

  int gE = (E_DIR_ + 255) / 256;
  hipMemsetAsync(degA, 0, (size_t)N_ENT * 4, stream);
  hipMemsetAsync(degB, 0, (size_t)N_ENT * 4, stream);
  deg_count<<<gE, 256, 0, stream>>>(src1, degA, E_DIR_);   // counts(orig src)
  deg_count<<<gE, 256, 0, stream>>>(src2, degB, E_DIR_);   // counts(orig dst)
  norm_build<<<gE, 256, 0, stream>>>(src1, dst1, degA, norm1, E_DIR_);
  norm_build<<<gE, 256, 0, stream>>>(src2, dst2, degB, norm2, E_DIR_);

  // CSR by dst. dir0 indeg = counts(dst1) = degB; dir1 indeg = counts(dst2) = degA.
  int nbScan = (N_ENT + SCHUNK - 1) / SCHUNK;
  scan_partial<<<nbScan, 256, 0, stream>>>(degB, part, N_ENT);
  scan_part_seq<<<1, 64, 0, stream>>>(part, nbScan);
  scan_final<<<nbScan, 256, 0, stream>>>(degB, part, starts0, cursor0, N_ENT, E_DIR_);
  fill_csr<<<gE, 256, 0, stream>>>(dst1, cursor0, csr0, E_DIR_);

  scan_partial<<<nbScan, 256, 0, stream>>>(degA, part, N_ENT);
  scan_part_seq<<<1, 64, 0, stream>>>(part, nbScan);
  scan_final<<<nbScan, 256, 0, stream>>>(degA, part, starts1, cursor1, N_ENT, E_DIR_);
  fill_csr<<<gE, 256, 0, stream>>>(dst2, cursor1, csr1, E_DIR_);

  const int* q_r   = quals;
  const int* q_e   = quals + 2 * NQ_;
  const int* q_eid = quals + 4 * NQ_;

  for (int layer = 0; layer < 2; layer++) {
    const float* rallf = layer ? rall2 : rall1;
    const unsigned short* rallbf = layer ? rall2_bf : rall1_bf;
    const unsigned short* lrelbf = layer ? lrel2_bf : lrel1_bf;
    const float* bias = layer ? b2 : b1;
    const unsigned short* w_q    = WB(layer ? 9 : 4);
    const unsigned short* w_loop = WB(layer ? 7 : 2);
    const unsigned short* w_rel  = WB(layer ? 8 : 3);
    const unsigned short* w_in   = WB(layer ? 5 : 0);
    const unsigned short* w_out  = WB(layer ? 6 : 1);

    float* r_dst = layer ? r_out : rall2;
    gemm_rel200<<<4, 256, 0, stream>>>(rallf, w_rel, r_dst, 200);
    if (layer == 0) {
      copy_row<<<1, 256, 0, stream>>>(loop_rel2, rall2 + (size_t)200 * D_, D_);
      conv_f32_bf16_vec<<<(201 * 50 + 255) / 256, 256, 0, stream>>>(rall2, rall2_bf, 201 * 50);
    }

    for (int dir = 0; dir < 2; dir++) {
      const int* et  = etype + dir * E_DIR_;
      const int* qr  = q_r + dir * NQ_;
      const int* qe  = q_e + dir * NQ_;
      const int* qid = q_eid + dir * NQ_;
      const int* s   = dir ? src2 : src1;
      const int* dd  = dir ? dst2 : dst1;
      const float* nm = dir ? norm2 : norm1;
      const int* sts = dir ? starts1 : starts0;
      const int* csr = dir ? csr1 : csr0;
      unsigned short* pre = dir ? pre1 : pre0;

      node_gather<<<(N_ENT + 3) / 4, 256, 0, stream>>>(sts, csr, s, et, nm, x_bf, rallbf, pre);
      gemm_qual<<<(NQ_ + 63) / 64, 256, 0, stream>>>(x_bf, rallbf, qe, qr, qid,
                                                     s, dd, nm, w_q, pre, NQ_);
    }

    gemm_node<<<(N_ENT + 63) / 64, 256, 0, stream>>>(
        pre0, pre1, x_bf, lrelbf, w_in, w_out, w_loop, bias,
        layer ? x_out : (float*)nullptr, x_bf, N_ENT);
  }

  gather_out<<<(B_ * 14 * 50 + 255) / 256, 256, 0, stream>>>(
      x_out, r_out, ent_ix, rel_ix, quals_ix, out);
}

// Round 2
// 2961.623 us; speedup vs baseline: 1.3447x; 1.3447x over previous
//
#include <hip/hip_runtime.h>
#include <cstdio>

// ---------------------------------------------------------------------------
// Round 5: B-stationary gemm_node rewrite.
//  - Weights (3 segs x N-third) persist in LDS (111 KB, 1 block/CU, 8 waves);
//    A streams from global directly into MFMA operand regs (per-lane uint4,
//    16x64B lines per instruction). One barrier per block; no inner barriers.
//  - N split 3 ways (5/5/3 col-tiles); partner blocks for the same rows are
//    co-resident on the same XCD (x=bid&7) so A re-reads hit L2.
//  - x ping-pong buffer (xb2) removes the in-place read/write race.
//  - fast exp2-based tanh (~7 VALU) replaces libm tanhf.
//  - gemm_qual reverted byte-for-byte to the round-3 version (the round-4
//    prefetch regressed: in-order vmcnt made every B-load wait on the
//    HBM prefetch).
// ---------------------------------------------------------------------------

#define ALPHA_MIX 0.8f

constexpr int N_ENT  = 200000;
constexpr int D_     = 200;
constexpr int E_DIR_ = 500000;
constexpr int NQ_    = 400000;
constexpr int B_     = 4096;

constexpr int NT_  = 13;   // 13 column tiles of 16 (208 padded, 200 used)
constexpr int LDA_ = 232;  // LDS A row stride in bf16 elements (gemm_qual/rel)
constexpr int WLD_ = 224;  // Bp row stride = padded K
constexpr int SB_  = 232;  // gemm_node LDS B stride (16B-aligned rows, 2-way max banking)
constexpr int PB_  = 80;   // max B rows (N-cols) per part
constexpr int NTILES_ = (N_ENT + 15) / 16;  // 12500 row-tiles

constexpr size_t OFS_SUB  = 0;
constexpr size_t OFS_REL  = 819200;
constexpr size_t OFS_QOBJ = 1638400;
constexpr size_t OFS_QREL = 6553600;
constexpr size_t OFS_X    = 11468800;
constexpr size_t OFS_R    = 51468800;

typedef __bf16 bf16x8 __attribute__((ext_vector_type(8)));
typedef float  f32x4  __attribute__((ext_vector_type(4)));

__device__ __forceinline__ unsigned int f2bf(float f) {
  unsigned int u = __float_as_uint(f);
  u += 0x7FFFu + ((u >> 16) & 1u);   // RNE
  return u >> 16;
}
__device__ __forceinline__ unsigned long long pack4bf(float x, float y, float z, float w) {
  return (unsigned long long)f2bf(x) | ((unsigned long long)f2bf(y) << 16) |
         ((unsigned long long)f2bf(z) << 32) | ((unsigned long long)f2bf(w) << 48);
}
__device__ __forceinline__ float bf_lo(unsigned int u) { return __uint_as_float(u << 16); }
__device__ __forceinline__ float bf_hi(unsigned int u) { return __uint_as_float(u & 0xFFFF0000u); }
__device__ __forceinline__ unsigned int mulpk(unsigned int a, unsigned int b) {
  return f2bf(bf_lo(a) * bf_lo(b)) | (f2bf(bf_hi(a) * bf_hi(b)) << 16);
}
__device__ __forceinline__ float fast_tanh(float x) {
  float xx = fminf(fmaxf(x, -9.0f), 9.0f);
  float e = __builtin_amdgcn_exp2f(xx * 2.8853900817779268f);  // e^(2x)
  return (e - 1.0f) * __builtin_amdgcn_rcpf(e + 1.0f);
}

typedef short v2s __attribute__((ext_vector_type(2)));
__device__ __forceinline__ void atomic_pk_add_bf16(unsigned short* addr, unsigned int pk) {
#if __has_builtin(__builtin_amdgcn_global_atomic_fadd_v2bf16)
  v2s v;
  __builtin_memcpy(&v, &pk, 4);
  __builtin_amdgcn_global_atomic_fadd_v2bf16(
      (__attribute__((address_space(1))) v2s*)(unsigned long long)addr, v);
#else
  unsigned int* ap = (unsigned int*)addr;
  unsigned int old = *ap;
  while (true) {
    unsigned int nv = f2bf(bf_lo(old) + bf_lo(pk)) | (f2bf(bf_hi(old) + bf_hi(pk)) << 16);
    unsigned int prev = atomicCAS(ap, old, nv);
    if (prev == old) break;
    old = prev;
  }
#endif
}

// ---------------------------------------------------------------------------
// Qual GEMM (round-3 form, reverted): rows = quals. A[row] = x_bf[q_e]*rall_bf[q_r];
// y = A@w_q. Epilogue: pre[dst[eid]] += 0.2*norm[eid] * x_bf[src[eid]] * y.
// ---------------------------------------------------------------------------
__global__ __launch_bounds__(256)
void gemm_qual(const unsigned short* __restrict__ Xbf, const unsigned short* __restrict__ Rbf,
               const int* __restrict__ q_e, const int* __restrict__ q_r,
               const int* __restrict__ q_eid,
               const int* __restrict__ srcv, const int* __restrict__ dstv,
               const float* __restrict__ nrm,
               const unsigned short* __restrict__ Bp,
               unsigned short* __restrict__ pre, int nrows)
{
  __shared__ __align__(16) unsigned short As[64 * LDA_];
  __shared__ int s_g[64], s_r[64], s_eid[64], s_dst[64];
  __shared__ float s_nm[64];

  const int t  = threadIdx.x;
  const int r0 = blockIdx.x * 64;

  if (t < 64) {
    int cr = min(r0 + t, nrows - 1);
    s_g[t] = q_e[cr]; s_r[t] = q_r[cr]; s_eid[t] = q_eid[cr];
  }
  __syncthreads();

  for (int task = t; task < 64 * 25; task += 256) {
    int i = task / 25, c = task % 25;
    uint4 xv = ((const uint4*)(Xbf + (size_t)s_g[i] * D_))[c];
    uint4 rv = ((const uint4*)(Rbf + (size_t)s_r[i] * D_))[c];
    uint4 o;
    o.x = mulpk(xv.x, rv.x); o.y = mulpk(xv.y, rv.y);
    o.z = mulpk(xv.z, rv.z); o.w = mulpk(xv.w, rv.w);
    *(uint4*)(As + i * LDA_ + c * 8) = o;
  }
  for (int task = t; task < 64 * 3; task += 256) {
    int i = task / 3, c = task % 3;
    *(uint4*)(As + i * LDA_ + 200 + c * 8) = make_uint4(0, 0, 0, 0);
  }
  __syncthreads();

  const int wave = t >> 6, lane = t & 63;
  const int m = lane & 15, quad = lane >> 4;

  f32x4 acc[NT_];
  const f32x4 zero = {0.f, 0.f, 0.f, 0.f};
  #pragma unroll
  for (int i = 0; i < NT_; i++) acc[i] = zero;

  {
    const unsigned short* arow = As + (wave * 16 + m) * LDA_ + quad * 8;
    const unsigned short* brow = Bp + (size_t)m * WLD_ + quad * 8;
    #pragma unroll
    for (int ks = 0; ks < 7; ks++) {
      bf16x8 av = *(const bf16x8*)(arow + ks * 32);
      #pragma unroll
      for (int tt = 0; tt < NT_; tt++) {
        bf16x8 bv = *(const bf16x8*)(brow + (size_t)tt * 16 * WLD_ + ks * 32);
        acc[tt] = __builtin_amdgcn_mfma_f32_16x16x32_bf16(av, bv, acc[tt], 0, 0, 0);
      }
    }
  }

  // restage LDS with x_bf[src[eid]] rows; gather edge metadata
  __syncthreads();
  if (t < 64) {
    int e = s_eid[t];
    s_dst[t] = dstv[e];
    s_nm[t]  = (1.0f - ALPHA_MIX) * nrm[e];
    s_g[t]   = srcv[e];
  }
  __syncthreads();
  for (int task = t; task < 64 * 25; task += 256) {
    int i = task / 25, c = task % 25;
    *(uint4*)(As + i * LDA_ + c * 8) = ((const uint4*)(Xbf + (size_t)s_g[i] * D_))[c];
  }
  __syncthreads();

  #pragma unroll
  for (int rg = 0; rg < 4; rg++) {
    int row = r0 + wave * 16 + quad * 4 + rg;
    bool valid = row < nrows;
    int li = row - r0;
    size_t orow = (size_t)s_dst[li] * D_;
    float nm = s_nm[li];
    #pragma unroll
    for (int tt = 0; tt < NT_; tt++) {
      int col = tt * 16 + m;
      float xv = (col < D_) ? __uint_as_float(((unsigned int)As[li * LDA_ + col]) << 16) : 0.0f;
      float v  = acc[tt][rg] * nm * xv;
      float vn = __shfl_xor(v, 1);
      if (valid && !(m & 1) && col < D_) {
        unsigned int pk = f2bf(v) | (f2bf(vn) << 16);
        atomic_pk_add_bf16(pre + orow + col, pk);
      }
    }
  }
}

// ---------------------------------------------------------------------------
// CSR-based node gather: pre[d] = 0.8 * sum_{e in(d)} norm*x[src]*rall[et]
// ---------------------------------------------------------------------------
__global__ __launch_bounds__(256)
void node_gather(const int* __restrict__ starts, const int* __restrict__ csr,
                 const int* __restrict__ srcv, const int* __restrict__ et,
                 const float* __restrict__ nrm,
                 const unsigned short* __restrict__ xbf,
                 const unsigned short* __restrict__ rallbf,
                 unsigned short* __restrict__ pre)
{
  int node = blockIdx.x * 4 + (threadIdx.x >> 6);
  if (node >= N_ENT) return;
  int lane = threadIdx.x & 63;
  int p0 = starts[node], p1 = starts[node + 1];
  float a0 = 0.f, a1 = 0.f, a2 = 0.f, a3 = 0.f;
  for (int p = p0; p < p1; p++) {
    int e = csr[p];
    int s = srcv[e], ty = et[e];
    float nm = nrm[e];
    if (lane < 50) {
      uint2 xv = ((const uint2*)(xbf + (size_t)s * D_))[lane];
      uint2 rv = ((const uint2*)(rallbf + (size_t)ty * D_))[lane];
      a0 += nm * bf_lo(xv.x) * bf_lo(rv.x);
      a1 += nm * bf_hi(xv.x) * bf_hi(rv.x);
      a2 += nm * bf_lo(xv.y) * bf_lo(rv.y);
      a3 += nm * bf_hi(xv.y) * bf_hi(rv.y);
    }
  }
  if (lane < 50) {
    uint2 o;
    o.x = f2bf(a0 * ALPHA_MIX) | (f2bf(a1 * ALPHA_MIX) << 16);
    o.y = f2bf(a2 * ALPHA_MIX) | (f2bf(a3 * ALPHA_MIX) << 16);
    ((uint2*)(pre + (size_t)node * D_))[lane] = o;
  }
}

// ---------------------------------------------------------------------------
// Node GEMM, B-stationary: weights for this block's N-part (3 segs) live in
// LDS; A (pre0|pre1|x*lrel rows) streams from global straight into MFMA
// operand registers. No barriers in the tile loop.
// ---------------------------------------------------------------------------
template<int NTH>
__device__ __forceinline__ void node_core(
    const unsigned short* Bl,
    const unsigned short* __restrict__ pre0,
    const unsigned short* __restrict__ pre1,
    const unsigned short* __restrict__ xsrc,
    const uint4* lv,
    const float* __restrict__ bias,
    float* __restrict__ xo, unsigned short* __restrict__ xbo,
    int rowblk, int wave, int m, int quad, int ncol0, int nrows)
{
  for (int i = wave; i < 49; i += 8) {
    int T = rowblk * 49 + i;
    if (T >= NTILES_) break;
    int rowi = min(T * 16 + m, nrows - 1);
    const unsigned short* a0 = pre0 + (size_t)rowi * D_ + quad * 8;
    const unsigned short* a1 = pre1 + (size_t)rowi * D_ + quad * 8;
    const unsigned short* a2 = xsrc + (size_t)rowi * D_ + quad * 8;

    // issue all 21 A-frag loads (seg0 first so counted vmcnt frees them first)
    uint4 af[3][7];
    #pragma unroll
    for (int ks = 0; ks < 7; ks++) af[0][ks] = *(const uint4*)(a0 + ks * 32);
    #pragma unroll
    for (int ks = 0; ks < 7; ks++) af[1][ks] = *(const uint4*)(a1 + ks * 32);
    #pragma unroll
    for (int ks = 0; ks < 7; ks++) af[2][ks] = *(const uint4*)(a2 + ks * 32);

    f32x4 acc[NTH];
    const f32x4 zero = {0.f, 0.f, 0.f, 0.f};
    #pragma unroll
    for (int tt = 0; tt < NTH; tt++) acc[tt] = zero;

    #pragma unroll
    for (int seg = 0; seg < 3; seg++) {
      #pragma unroll
      for (int ks = 0; ks < 7; ks++) {
        uint4 a = af[seg][ks];
        if (seg == 2) {  // compose x * loop_rel at consumption time
          a.x = mulpk(a.x, lv[ks].x); a.y = mulpk(a.y, lv[ks].y);
          a.z = mulpk(a.z, lv[ks].z); a.w = mulpk(a.w, lv[ks].w);
        }
        bf16x8 av; __builtin_memcpy(&av, &a, 16);
        #pragma unroll
        for (int tt = 0; tt < NTH; tt++) {
          const unsigned short* bp = Bl + (size_t)(seg * PB_ + tt * 16 + m) * SB_ + quad * 8 + ks * 32;
          bf16x8 bv = *(const bf16x8*)bp;
          acc[tt] = __builtin_amdgcn_mfma_f32_16x16x32_bf16(av, bv, acc[tt], 0, 0, 0);
        }
      }
    }

    #pragma unroll
    for (int rg = 0; rg < 4; rg++) {
      int row = T * 16 + quad * 4 + rg;
      if (row < nrows) {
        #pragma unroll
        for (int tt = 0; tt < NTH; tt++) {
          int col = ncol0 + tt * 16 + m;
          if (col < D_) {
            float v = acc[tt][rg] * (1.0f / 3.0f) + bias[col];
            float th = fast_tanh(v);
            if (xo)  xo[(size_t)row * D_ + col] = th;
            if (xbo) xbo[(size_t)row * D_ + col] = (unsigned short)f2bf(th);
          }
        }
      }
    }
  }
}

__global__ __launch_bounds__(512)
void gemm_node(const unsigned short* __restrict__ pre0,
               const unsigned short* __restrict__ pre1,
               const unsigned short* __restrict__ xsrc,
               const unsigned short* __restrict__ lrel,
               const unsigned short* __restrict__ B0,
               const unsigned short* __restrict__ B1,
               const unsigned short* __restrict__ B2,
               const float* __restrict__ bias,
               float* __restrict__ xo, unsigned short* __restrict__ xbo,
               int nrows)
{
  __shared__ __align__(16) unsigned short Bl[3 * PB_ * SB_];  // 111,360 B
  const int t   = threadIdx.x;
  const int bid = blockIdx.x;
  // bid = q*8 + x; partners (same rows, parts 0..2) are q,q+1,q+2 with same
  // x (= XCD) -> co-resident on one XCD, A re-reads hit that XCD's L2.
  const int x8 = bid & 7, q = bid >> 3;
  const int part   = q % 3;
  const int rowblk = (q / 3) * 8 + x8;          // 0..255
  const int nth    = (part == 2) ? 3 : 5;
  const int ncol0  = part * PB_;
  const int nrB    = nth * 16;

  const unsigned short* Bs[3] = {B0, B1, B2};
  for (int task = t; task < 3 * nrB * 28; task += 512) {
    int seg = task / (nrB * 28);
    int rem = task % (nrB * 28);
    int n = rem / 28, c = rem % 28;
    uint4 v = *(const uint4*)(Bs[seg] + (size_t)(ncol0 + n) * WLD_ + c * 8);
    *(uint4*)(Bl + (size_t)(seg * PB_ + n) * SB_ + c * 8) = v;
  }
  __syncthreads();

  const int wave = t >> 6, lane = t & 63;
  const int m = lane & 15, quad = lane >> 4;

  uint4 lv[7];
  #pragma unroll
  for (int ks = 0; ks < 7; ks++)
    lv[ks] = *(const uint4*)(lrel + quad * 8 + ks * 32);

  if (part == 2)
    node_core<3>(Bl, pre0, pre1, xsrc, lv, bias, xo, xbo, rowblk, wave, m, quad, ncol0, nrows);
  else
    node_core<5>(Bl, pre0, pre1, xsrc, lv, bias, xo, xbo, rowblk, wave, m, quad, ncol0, nrows);
}

// ---------------------------------------------------------------------------
__global__ __launch_bounds__(256)
void gemm_rel200(const float* __restrict__ X, const unsigned short* __restrict__ Bp,
                 float* __restrict__ Out, int nrows)
{
  __shared__ __align__(16) unsigned short As[64 * LDA_];
  const int t  = threadIdx.x;
  const int r0 = blockIdx.x * 64;

  for (int task = t; task < 64 * 50; task += 256) {
    int i = task / 50, c = task % 50;
    int cr = min(r0 + i, nrows - 1);
    float4 xv = ((const float4*)(X + (size_t)cr * D_))[c];
    *(unsigned long long*)&As[i * LDA_ + c * 4] = pack4bf(xv.x, xv.y, xv.z, xv.w);
  }
  for (int task = t; task < 64 * 6; task += 256) {
    int i = task / 6, c = task % 6;
    *(unsigned long long*)&As[i * LDA_ + 200 + c * 4] = 0ull;
  }
  __syncthreads();

  const int wave = t >> 6, lane = t & 63;
  const int m = lane & 15, quad = lane >> 4;

  f32x4 acc[NT_];
  const f32x4 zero = {0.f, 0.f, 0.f, 0.f};
  #pragma unroll
  for (int i = 0; i < NT_; i++) acc[i] = zero;

  const unsigned short* arow = As + (wave * 16 + m) * LDA_ + quad * 8;
  const unsigned short* brow = Bp + (size_t)m * WLD_ + quad * 8;
  #pragma unroll
  for (int ks = 0; ks < 7; ks++) {
    bf16x8 av = *(const bf16x8*)(arow + ks * 32);
    #pragma unroll
    for (int tt = 0; tt < NT_; tt++) {
      bf16x8 bv = *(const bf16x8*)(brow + (size_t)tt * 16 * WLD_ + ks * 32);
      acc[tt] = __builtin_amdgcn_mfma_f32_16x16x32_bf16(av, bv, acc[tt], 0, 0, 0);
    }
  }

  #pragma unroll
  for (int rg = 0; rg < 4; rg++) {
    int row = r0 + wave * 16 + quad * 4 + rg;
    if (row < nrows) {
      #pragma unroll
      for (int tt = 0; tt < NT_; tt++) {
        int col = tt * 16 + m;
        if (col < D_) Out[(size_t)row * D_ + col] = acc[tt][rg];
      }
    }
  }
}

// ---------------------------------------------------------------------------
struct WP10 { const float* p[10]; };

__global__ void convert_weights(WP10 wp, unsigned short* __restrict__ wbp) {
  int i = blockIdx.x * 256 + threadIdx.x;
  if (i < 10 * 208 * WLD_) {
    int j = i / (208 * WLD_);
    int rem = i % (208 * WLD_);
    int n = rem / WLD_, k = rem % WLD_;
    float v = (n < D_ && k < D_) ? wp.p[j][(size_t)k * D_ + n] : 0.0f;  // Bp[n][k]=w[k][n]
    wbp[i] = (unsigned short)f2bf(v);
  }
}

__global__ void conv_f32_bf16_vec(const float* __restrict__ src,
                                  unsigned short* __restrict__ dst, int n4) {
  int i = blockIdx.x * 256 + threadIdx.x;
  if (i < n4) {
    float4 v = ((const float4*)src)[i];
    uint2 o;
    o.x = f2bf(v.x) | (f2bf(v.y) << 16);
    o.y = f2bf(v.z) | (f2bf(v.w) << 16);
    ((uint2*)dst)[i] = o;
  }
}

__global__ void build_rall(const float* __restrict__ rel_embs,
                           const float* __restrict__ loop_rel,
                           float* __restrict__ rall) {
  int i = blockIdx.x * 256 + threadIdx.x;
  if (i < 201 * D_) rall[i] = (i < 200 * D_) ? rel_embs[i] : loop_rel[i - 200 * D_];
}

__global__ void copy_row(const float* __restrict__ src, float* __restrict__ dst, int n) {
  int i = blockIdx.x * 256 + threadIdx.x;
  if (i < n) dst[i] = src[i];
}

__global__ void deg_count(const int* __restrict__ src, int* __restrict__ deg, int E) {
  int e = blockIdx.x * 256 + threadIdx.x;
  if (e < E) atomicAdd(&deg[src[e]], 1);
}

__global__ void norm_build(const int* __restrict__ src, const int* __restrict__ dst,
                           const int* __restrict__ deg, float* __restrict__ nrm, int E) {
  int e = blockIdx.x * 256 + threadIdx.x;
  if (e < E) {
    int a = deg[src[e]], b = deg[dst[e]];
    float fa = (a > 0) ? rsqrtf((float)a) : 0.0f;
    float fb = (b > 0) ? rsqrtf((float)b) : 0.0f;
    nrm[e] = fa * fb;
  }
}

// ---- exclusive scan (3 kernels) + CSR fill -------------------------------
constexpr int SCHUNK = 2048;

__global__ void scan_partial(const int* __restrict__ in, int* __restrict__ part, int n) {
  __shared__ int red[256];
  int b = blockIdx.x, t = threadIdx.x;
  int base = b * SCHUNK + t * 8;
  int s = 0;
  #pragma unroll
  for (int j = 0; j < 8; j++) { int i = base + j; if (i < n) s += in[i]; }
  red[t] = s; __syncthreads();
  for (int off = 128; off > 0; off >>= 1) {
    if (t < off) red[t] += red[t + off];
    __syncthreads();
  }
  if (t == 0) part[b] = red[0];
}

__global__ void scan_part_seq(int* part, int nb) {
  if (threadIdx.x == 0 && blockIdx.x == 0) {
    int run = 0;
    for (int i = 0; i < nb; i++) { int v = part[i]; part[i] = run; run += v; }
  }
}

__global__ void scan_final(const int* __restrict__ in, const int* __restrict__ part,
                           int* __restrict__ outs, int* __restrict__ cursor,
                           int n, int total) {
  __shared__ int buf[256];
  int b = blockIdx.x, t = threadIdx.x;
  int base = b * SCHUNK + t * 8;
  int v[8]; int s = 0;
  #pragma unroll
  for (int j = 0; j < 8; j++) { int i = base + j; v[j] = (i < n) ? in[i] : 0; s += v[j]; }
  buf[t] = s; __syncthreads();
  for (int off = 1; off < 256; off <<= 1) {
    int add = (t >= off) ? buf[t - off] : 0;
    __syncthreads();
    buf[t] += add;
    __syncthreads();
  }
  int excl = buf[t] - s + part[b];
  #pragma unroll
  for (int j = 0; j < 8; j++) {
    int i = base + j;
    if (i < n) { outs[i] = excl; cursor[i] = excl; }
    excl += v[j];
  }
  if (b == 0 && t == 0) outs[n] = total;
}

__global__ void fill_csr(const int* __restrict__ dstv, int* __restrict__ cursor,
                         int* __restrict__ csr, int E) {
  int e = blockIdx.x * 256 + threadIdx.x;
  if (e < E) {
    int pos = atomicAdd(&cursor[dstv[e]], 1);
    csr[pos] = e;
  }
}

__global__ void gather_out(const float* __restrict__ x2, const float* __restrict__ r2,
                           const int* __restrict__ ent_ix, const int* __restrict__ rel_ix,
                           const int* __restrict__ quals_ix, float* __restrict__ out) {
  int i = blockIdx.x * 256 + threadIdx.x;
  if (i >= B_ * 14 * 50) return;
  int b = i / 700, rem = i % 700, slot = rem / 50, c = rem % 50;
  const float* srcrow; float* dstrow;
  if (slot == 0)      { srcrow = x2 + (size_t)ent_ix[b] * D_;  dstrow = out + OFS_SUB + (size_t)b * D_; }
  else if (slot == 1) { srcrow = r2 + (size_t)rel_ix[b] * D_;  dstrow = out + OFS_REL + (size_t)b * D_; }
  else if (slot < 8)  { int j = slot - 2;
                        srcrow = x2 + (size_t)quals_ix[b * 12 + 2 * j + 1] * D_;
                        dstrow = out + OFS_QOBJ + ((size_t)b * 6 + j) * D_; }
  else                { int j = slot - 8;
                        srcrow = r2 + (size_t)quals_ix[b * 12 + 2 * j] * D_;
                        dstrow = out + OFS_QREL + ((size_t)b * 6 + j) * D_; }
  ((float4*)dstrow)[c] = ((const float4*)srcrow)[c];
}

// ---------------------------------------------------------------------------
extern "C" void kernel_launch(void* const* d_in, const int* in_sizes, int n_in,
                              void* d_out, int out_size, void* d_ws, size_t ws_size,
                              hipStream_t stream)
{
  const float* ent       = (const float*)d_in[0];
  const float* rel_embs  = (const float*)d_in[1];
  const float* loop_rel1 = (const float*)d_in[12];
  const float* loop_rel2 = (const float*)d_in[13];
  const float* b1        = (const float*)d_in[14];
  const float* b2        = (const float*)d_in[15];
  const int*   ei        = (const int*)d_in[16];
  const int*   etype     = (const int*)d_in[17];
  const int*   quals     = (const int*)d_in[18];
  const int*   ent_ix    = (const int*)d_in[19];
  const int*   rel_ix    = (const int*)d_in[20];
  const int*   quals_ix  = (const int*)d_in[21];

  char* wsb = (char*)d_ws;
  size_t off = 0;
  auto walloc = [&](size_t bytes) -> char* {
    char* p = wsb + off; off += (bytes + 511) & ~(size_t)511; return p;
  };
  unsigned short* pre0  = (unsigned short*)walloc((size_t)N_ENT * D_ * 2);   // 80 MB
  unsigned short* pre1  = (unsigned short*)walloc((size_t)N_ENT * D_ * 2);   // 80 MB
  unsigned short* x_bf  = (unsigned short*)walloc((size_t)N_ENT * D_ * 2);   // 80 MB
  unsigned short* xb2   = (unsigned short*)walloc((size_t)N_ENT * D_ * 2);   // 80 MB (ping-pong)
  float* norm1 = (float*)walloc((size_t)E_DIR_ * 4);
  float* norm2 = (float*)walloc((size_t)E_DIR_ * 4);
  int*   degA  = (int*)walloc((size_t)N_ENT * 4);   // counts of orig src
  int*   degB  = (int*)walloc((size_t)N_ENT * 4);   // counts of orig dst
  int*   starts0 = (int*)walloc((size_t)(N_ENT + 1) * 4);
  int*   starts1 = (int*)walloc((size_t)(N_ENT + 1) * 4);
  int*   cursor0 = (int*)walloc((size_t)N_ENT * 4);
  int*   cursor1 = (int*)walloc((size_t)N_ENT * 4);
  int*   csr0    = (int*)walloc((size_t)E_DIR_ * 4);
  int*   csr1    = (int*)walloc((size_t)E_DIR_ * 4);
  int*   part    = (int*)walloc((size_t)256 * 4);
  float* rall1 = (float*)walloc((size_t)201 * D_ * 4);
  float* rall2 = (float*)walloc((size_t)201 * D_ * 4);
  unsigned short* rall1_bf = (unsigned short*)walloc((size_t)201 * D_ * 2);
  unsigned short* rall2_bf = (unsigned short*)walloc((size_t)201 * D_ * 2);
  unsigned short* lrel1_bf = (unsigned short*)walloc((size_t)D_ * 2);
  unsigned short* lrel2_bf = (unsigned short*)walloc((size_t)D_ * 2);
  unsigned short* wbp = (unsigned short*)walloc((size_t)10 * 208 * WLD_ * 2);
  if (off > ws_size) fprintf(stderr, "ws overflow: need %zu have %zu\n", off, ws_size);

  float* out   = (float*)d_out;
  float* x_out = out + OFS_X;
  float* r_out = out + OFS_R;

  auto WB = [&](int j) { return wbp + (size_t)j * 208 * WLD_; };

  WP10 wp; for (int j = 0; j < 10; j++) wp.p[j] = (const float*)d_in[2 + j];
  convert_weights<<<(10 * 208 * WLD_ + 255) / 256, 256, 0, stream>>>(wp, wbp);
  build_rall<<<(201 * D_ + 255) / 256, 256, 0, stream>>>(rel_embs, loop_rel1, rall1);
  conv_f32_bf16_vec<<<(201 * 50 + 255) / 256, 256, 0, stream>>>(rall1, rall1_bf, 201 * 50);
  conv_f32_bf16_vec<<<(N_ENT * 50 + 255) / 256, 256, 0, stream>>>(ent, x_bf, N_ENT * 50);
  conv_f32_bf16_vec<<<1, 256, 0, stream>>>(loop_rel1, lrel1_bf, 50);
  conv_f32_bf16_vec<<<1, 256, 0, stream>>>(loop_rel2, lrel2_bf, 50);

  const int* src1 = ei;                // dir0 src = orig src
  const int* dst1 = ei + 2 * E_DIR_;   // dir0 dst = orig dst
  const int* src2 = ei + E_DIR_;       // dir1 src = orig dst
  const int* dst2 = ei + 3 * E_DIR_;   // dir1 dst = orig src

  int gE = (E_DIR_ + 255) / 256;
  hipMemsetAsync(degA, 0, (size_t)N_ENT * 4, stream);
  hipMemsetAsync(degB, 0, (size_t)N_ENT * 4, stream);
  deg_count<<<gE, 256, 0, stream>>>(src1, degA, E_DIR_);   // counts(orig src)
  deg_count<<<gE, 256, 0, stream>>>(src2, degB, E_DIR_);   // counts(orig dst)
  norm_build<<<gE, 256, 0, stream>>>(src1, dst1, degA, norm1, E_DIR_);
  norm_build<<<gE, 256, 0, stream>>>(src2, dst2, degB, norm2, E_DIR_);

  // CSR by dst. dir0 indeg = counts(dst1) = degB; dir1 indeg = counts(dst2) = degA.
  int nbScan = (N_ENT + SCHUNK - 1) / SCHUNK;
  scan_partial<<<nbScan, 256, 0, stream>>>(degB, part, N_ENT);
  scan_part_seq<<<1, 64, 0, stream>>>(part, nbScan);
  scan_final<<<nbScan, 256, 0, stream>>>(degB, part, starts0, cursor0, N_ENT, E_DIR_);
  fill_csr<<<gE, 256, 0, stream>>>(dst1, cursor0, csr0, E_DIR_);

  scan_partial<<<nbScan, 256, 0, stream>>>(degA, part, N_ENT);
  scan_part_seq<<<1, 64, 0, stream>>>(part, nbScan);
  scan_final<<<nbScan, 256, 0, stream>>>(degA, part, starts1, cursor1, N_ENT, E_DIR_);
  fill_csr<<<gE, 256, 0, stream>>>(dst2, cursor1, csr1, E_DIR_);

  const int* q_r   = quals;
  const int* q_e   = quals + 2 * NQ_;
  const int* q_eid = quals + 4 * NQ_;

  for (int layer = 0; layer < 2; layer++) {
    const float* rallf = layer ? rall2 : rall1;
    const unsigned short* rallbf = layer ? rall2_bf : rall1_bf;
    const unsigned short* lrelbf = layer ? lrel2_bf : lrel1_bf;
    const float* bias = layer ? b2 : b1;
    const unsigned short* w_q    = WB(layer ? 9 : 4);
    const unsigned short* w_loop = WB(layer ? 7 : 2);
    const unsigned short* w_rel  = WB(layer ? 8 : 3);
    const unsigned short* w_in   = WB(layer ? 5 : 0);
    const unsigned short* w_out  = WB(layer ? 6 : 1);
    const unsigned short* xin    = layer ? xb2 : x_bf;   // ping-pong

    float* r_dst = layer ? r_out : rall2;
    gemm_rel200<<<4, 256, 0, stream>>>(rallf, w_rel, r_dst, 200);
    if (layer == 0) {
      copy_row<<<1, 256, 0, stream>>>(loop_rel2, rall2 + (size_t)200 * D_, D_);
      conv_f32_bf16_vec<<<(201 * 50 + 255) / 256, 256, 0, stream>>>(rall2, rall2_bf, 201 * 50);
    }

    for (int dir = 0; dir < 2; dir++) {
      const int* et  = etype + dir * E_DIR_;
      const int* qr  = q_r + dir * NQ_;
      const int* qe  = q_e + dir * NQ_;
      const int* qid = q_eid + dir * NQ_;
      const int* s   = dir ? src2 : src1;
      const int* dd  = dir ? dst2 : dst1;
      const float* nm = dir ? norm2 : norm1;
      const int* sts = dir ? starts1 : starts0;
      const int* csr = dir ? csr1 : csr0;
      unsigned short* pre = dir ? pre1 : pre0;

      node_gather<<<(N_ENT + 3) / 4, 256, 0, stream>>>(sts, csr, s, et, nm, xin, rallbf, pre);
      gemm_qual<<<(NQ_ + 63) / 64, 256, 0, stream>>>(xin, rallbf, qe, qr, qid,
                                                     s, dd, nm, w_q, pre, NQ_);
    }

    // B-stationary node GEMM: grid = 256 rowblks x 3 N-parts, XCD-paired.
    if (layer == 0)
      gemm_node<<<768, 512, 0, stream>>>(pre0, pre1, xin, lrelbf,
                                         w_in, w_out, w_loop, bias,
                                         (float*)nullptr, xb2, N_ENT);
    else
      gemm_node<<<768, 512, 0, stream>>>(pre0, pre1, xin, lrelbf,
                                         w_in, w_out, w_loop, bias,
                                         x_out, (unsigned short*)nullptr, N_ENT);
  }

  gather_out<<<(B_ * 14 * 50 + 255) / 256, 256, 0, stream>>>(
      x_out, r_out, ent_ix, rel_ix, quals_ix, out);
}

// Round 3
// 2765.986 us; speedup vs baseline: 1.4398x; 1.0707x over previous
//
#include <hip/hip_runtime.h>
#include <cstdio>

// ---------------------------------------------------------------------------
// Round 6: edge-major qual path; atomics eliminated.
//  - Prolog builds per-direction qual-CSR (quals grouped by edge) and a
//    compact covered-edge list (edges with >=1 qual, ~55%).
//  - gemm_qedge: rows = covered edges. A[row] = sum_{quals of e} x[q_e]*r[q_r]
//    (f32 accumulate in regs), y = A @ w_q -> compact contiguous y buffer.
//    No atomics, no x[src] restage.
//  - node_gather folds the qual term: pre[d] = sum nrm*x[src] (x)
//    (0.8*rall[et] + 0.2*y[e]); f32 accum, single bf16 round (precision up).
//  - gemm_node / gemm_rel200 unchanged from round 5 (B-stationary win kept).
// ---------------------------------------------------------------------------

#define ALPHA_MIX 0.8f

constexpr int N_ENT  = 200000;
constexpr int D_     = 200;
constexpr int E_DIR_ = 500000;
constexpr int NQ_    = 400000;
constexpr int B_     = 4096;

constexpr int NT_  = 13;   // 13 column tiles of 16 (208 padded, 200 used)
constexpr int LDA_ = 232;  // LDS A row stride in bf16 elements
constexpr int WLD_ = 224;  // Bp row stride = padded K
constexpr int SB_  = 232;  // gemm_node LDS B stride
constexpr int PB_  = 80;   // max B rows (N-cols) per part
constexpr int NTILES_ = (N_ENT + 15) / 16;  // 12500 row-tiles

constexpr size_t OFS_SUB  = 0;
constexpr size_t OFS_REL  = 819200;
constexpr size_t OFS_QOBJ = 1638400;
constexpr size_t OFS_QREL = 6553600;
constexpr size_t OFS_X    = 11468800;
constexpr size_t OFS_R    = 51468800;

typedef __bf16 bf16x8 __attribute__((ext_vector_type(8)));
typedef float  f32x4  __attribute__((ext_vector_type(4)));

__device__ __forceinline__ unsigned int f2bf(float f) {
  unsigned int u = __float_as_uint(f);
  u += 0x7FFFu + ((u >> 16) & 1u);   // RNE
  return u >> 16;
}
__device__ __forceinline__ unsigned long long pack4bf(float x, float y, float z, float w) {
  return (unsigned long long)f2bf(x) | ((unsigned long long)f2bf(y) << 16) |
         ((unsigned long long)f2bf(z) << 32) | ((unsigned long long)f2bf(w) << 48);
}
__device__ __forceinline__ float bf_lo(unsigned int u) { return __uint_as_float(u << 16); }
__device__ __forceinline__ float bf_hi(unsigned int u) { return __uint_as_float(u & 0xFFFF0000u); }
__device__ __forceinline__ unsigned int mulpk(unsigned int a, unsigned int b) {
  return f2bf(bf_lo(a) * bf_lo(b)) | (f2bf(bf_hi(a) * bf_hi(b)) << 16);
}
__device__ __forceinline__ float fast_tanh(float x) {
  float xx = fminf(fmaxf(x, -9.0f), 9.0f);
  float e = __builtin_amdgcn_exp2f(xx * 2.8853900817779268f);  // e^(2x)
  return (e - 1.0f) * __builtin_amdgcn_rcpf(e + 1.0f);
}

// ---------------------------------------------------------------------------
// Qual-edge GEMM: rows = covered edges (compact). A[row] = f32 sum over the
// edge's quals of x_bf[q_e]*rall_bf[q_r]; y[row] = A @ w_q (bf16, contiguous).
// ---------------------------------------------------------------------------
__global__ __launch_bounds__(256)
void gemm_qedge(const unsigned short* __restrict__ Xbf, const unsigned short* __restrict__ Rbf,
                const int* __restrict__ q_e, const int* __restrict__ q_r,
                const int* __restrict__ qstarts, const int* __restrict__ qcsr,
                const int* __restrict__ covlist, const int* __restrict__ ncovp,
                const unsigned short* __restrict__ Bp,
                unsigned short* __restrict__ y)
{
  __shared__ __align__(16) unsigned short As[64 * LDA_];
  __shared__ int s_p0[64], s_p1[64];

  const int ncov = ncovp[0];
  const int r0 = blockIdx.x * 64;
  if (r0 >= ncov) return;
  const int t = threadIdx.x;

  if (t < 64) {
    int ce = r0 + t;
    if (ce < ncov) { int e = covlist[ce]; s_p0[t] = qstarts[e]; s_p1[t] = qstarts[e + 1]; }
    else           { s_p0[t] = 0; s_p1[t] = 0; }
  }
  __syncthreads();

  // compose: f32 register accumulation over this edge's quals, one bf16 round
  for (int task = t; task < 64 * 25; task += 256) {
    int i = task / 25, c = task % 25;
    float a0=0,a1=0,a2=0,a3=0,a4=0,a5=0,a6=0,a7=0;
    for (int p = s_p0[i]; p < s_p1[i]; p++) {
      int q = qcsr[p];
      uint4 xv = ((const uint4*)(Xbf + (size_t)q_e[q] * D_))[c];
      uint4 rv = ((const uint4*)(Rbf + (size_t)q_r[q] * D_))[c];
      a0 += bf_lo(xv.x) * bf_lo(rv.x); a1 += bf_hi(xv.x) * bf_hi(rv.x);
      a2 += bf_lo(xv.y) * bf_lo(rv.y); a3 += bf_hi(xv.y) * bf_hi(rv.y);
      a4 += bf_lo(xv.z) * bf_lo(rv.z); a5 += bf_hi(xv.z) * bf_hi(rv.z);
      a6 += bf_lo(xv.w) * bf_lo(rv.w); a7 += bf_hi(xv.w) * bf_hi(rv.w);
    }
    uint4 o;
    o.x = f2bf(a0) | (f2bf(a1) << 16); o.y = f2bf(a2) | (f2bf(a3) << 16);
    o.z = f2bf(a4) | (f2bf(a5) << 16); o.w = f2bf(a6) | (f2bf(a7) << 16);
    *(uint4*)(As + i * LDA_ + c * 8) = o;
  }
  for (int task = t; task < 64 * 3; task += 256) {
    int i = task / 3, c = task % 3;
    *(uint4*)(As + i * LDA_ + 200 + c * 8) = make_uint4(0, 0, 0, 0);
  }
  __syncthreads();

  const int wave = t >> 6, lane = t & 63;
  const int m = lane & 15, quad = lane >> 4;

  f32x4 acc[NT_];
  const f32x4 zero = {0.f, 0.f, 0.f, 0.f};
  #pragma unroll
  for (int i = 0; i < NT_; i++) acc[i] = zero;

  {
    const unsigned short* arow = As + (wave * 16 + m) * LDA_ + quad * 8;
    const unsigned short* brow = Bp + (size_t)m * WLD_ + quad * 8;
    #pragma unroll
    for (int ks = 0; ks < 7; ks++) {
      bf16x8 av = *(const bf16x8*)(arow + ks * 32);
      #pragma unroll
      for (int tt = 0; tt < NT_; tt++) {
        bf16x8 bv = *(const bf16x8*)(brow + (size_t)tt * 16 * WLD_ + ks * 32);
        acc[tt] = __builtin_amdgcn_mfma_f32_16x16x32_bf16(av, bv, acc[tt], 0, 0, 0);
      }
    }
  }

  #pragma unroll
  for (int rg = 0; rg < 4; rg++) {
    int row = r0 + wave * 16 + quad * 4 + rg;
    bool valid = row < ncov;
    #pragma unroll
    for (int tt = 0; tt < NT_; tt++) {
      int col = tt * 16 + m;
      float v  = acc[tt][rg];
      float vn = __shfl_xor(v, 1);
      if (valid && !(m & 1) && col < D_) {
        *(unsigned int*)(y + (size_t)row * D_ + col) = f2bf(v) | (f2bf(vn) << 16);
      }
    }
  }
}

// ---------------------------------------------------------------------------
// CSR-based node gather, qual-fused:
//   pre[d] = sum_{e in(d)} nrm[e] * x[src[e]] (x) (0.8*rall[et] + 0.2*y[e])
// f32 accumulation, single bf16 round.
// ---------------------------------------------------------------------------
__global__ __launch_bounds__(256)
void node_gather(const int* __restrict__ starts, const int* __restrict__ csr,
                 const int* __restrict__ srcv, const int* __restrict__ et,
                 const float* __restrict__ nrm,
                 const int* __restrict__ qidx, const unsigned short* __restrict__ y,
                 const unsigned short* __restrict__ xbf,
                 const unsigned short* __restrict__ rallbf,
                 unsigned short* __restrict__ pre)
{
  int node = blockIdx.x * 4 + (threadIdx.x >> 6);
  if (node >= N_ENT) return;
  int lane = threadIdx.x & 63;
  int p0 = starts[node], p1 = starts[node + 1];
  float a0 = 0.f, a1 = 0.f, a2 = 0.f, a3 = 0.f;
  for (int p = p0; p < p1; p++) {
    int e = csr[p];
    int s = srcv[e], ty = et[e], qi = qidx[e];
    float nm = nrm[e];
    if (lane < 50) {
      uint2 xv = ((const uint2*)(xbf + (size_t)s * D_))[lane];
      uint2 rv = ((const uint2*)(rallbf + (size_t)ty * D_))[lane];
      float c0 = ALPHA_MIX * bf_lo(rv.x), c1 = ALPHA_MIX * bf_hi(rv.x);
      float c2 = ALPHA_MIX * bf_lo(rv.y), c3 = ALPHA_MIX * bf_hi(rv.y);
      if (qi >= 0) {
        uint2 yv = ((const uint2*)(y + (size_t)qi * D_))[lane];
        c0 = fmaf(1.0f - ALPHA_MIX, bf_lo(yv.x), c0);
        c1 = fmaf(1.0f - ALPHA_MIX, bf_hi(yv.x), c1);
        c2 = fmaf(1.0f - ALPHA_MIX, bf_lo(yv.y), c2);
        c3 = fmaf(1.0f - ALPHA_MIX, bf_hi(yv.y), c3);
      }
      a0 = fmaf(nm * bf_lo(xv.x), c0, a0);
      a1 = fmaf(nm * bf_hi(xv.x), c1, a1);
      a2 = fmaf(nm * bf_lo(xv.y), c2, a2);
      a3 = fmaf(nm * bf_hi(xv.y), c3, a3);
    }
  }
  if (lane < 50) {
    uint2 o;
    o.x = f2bf(a0) | (f2bf(a1) << 16);
    o.y = f2bf(a2) | (f2bf(a3) << 16);
    ((uint2*)(pre + (size_t)node * D_))[lane] = o;
  }
}

// ---------------------------------------------------------------------------
// Node GEMM, B-stationary (unchanged from round 5).
// ---------------------------------------------------------------------------
template<int NTH>
__device__ __forceinline__ void node_core(
    const unsigned short* Bl,
    const unsigned short* __restrict__ pre0,
    const unsigned short* __restrict__ pre1,
    const unsigned short* __restrict__ xsrc,
    const uint4* lv,
    const float* __restrict__ bias,
    float* __restrict__ xo, unsigned short* __restrict__ xbo,
    int rowblk, int wave, int m, int quad, int ncol0, int nrows)
{
  for (int i = wave; i < 49; i += 8) {
    int T = rowblk * 49 + i;
    if (T >= NTILES_) break;
    int rowi = min(T * 16 + m, nrows - 1);
    const unsigned short* a0 = pre0 + (size_t)rowi * D_ + quad * 8;
    const unsigned short* a1 = pre1 + (size_t)rowi * D_ + quad * 8;
    const unsigned short* a2 = xsrc + (size_t)rowi * D_ + quad * 8;

    uint4 af[3][7];
    #pragma unroll
    for (int ks = 0; ks < 7; ks++) af[0][ks] = *(const uint4*)(a0 + ks * 32);
    #pragma unroll
    for (int ks = 0; ks < 7; ks++) af[1][ks] = *(const uint4*)(a1 + ks * 32);
    #pragma unroll
    for (int ks = 0; ks < 7; ks++) af[2][ks] = *(const uint4*)(a2 + ks * 32);

    f32x4 acc[NTH];
    const f32x4 zero = {0.f, 0.f, 0.f, 0.f};
    #pragma unroll
    for (int tt = 0; tt < NTH; tt++) acc[tt] = zero;

    #pragma unroll
    for (int seg = 0; seg < 3; seg++) {
      #pragma unroll
      for (int ks = 0; ks < 7; ks++) {
        uint4 a = af[seg][ks];
        if (seg == 2) {
          a.x = mulpk(a.x, lv[ks].x); a.y = mulpk(a.y, lv[ks].y);
          a.z = mulpk(a.z, lv[ks].z); a.w = mulpk(a.w, lv[ks].w);
        }
        bf16x8 av; __builtin_memcpy(&av, &a, 16);
        #pragma unroll
        for (int tt = 0; tt < NTH; tt++) {
          const unsigned short* bp = Bl + (size_t)(seg * PB_ + tt * 16 + m) * SB_ + quad * 8 + ks * 32;
          bf16x8 bv = *(const bf16x8*)bp;
          acc[tt] = __builtin_amdgcn_mfma_f32_16x16x32_bf16(av, bv, acc[tt], 0, 0, 0);
        }
      }
    }

    #pragma unroll
    for (int rg = 0; rg < 4; rg++) {
      int row = T * 16 + quad * 4 + rg;
      if (row < nrows) {
        #pragma unroll
        for (int tt = 0; tt < NTH; tt++) {
          int col = ncol0 + tt * 16 + m;
          if (col < D_) {
            float v = acc[tt][rg] * (1.0f / 3.0f) + bias[col];
            float th = fast_tanh(v);
            if (xo)  xo[(size_t)row * D_ + col] = th;
            if (xbo) xbo[(size_t)row * D_ + col] = (unsigned short)f2bf(th);
          }
        }
      }
    }
  }
}

__global__ __launch_bounds__(512)
void gemm_node(const unsigned short* __restrict__ pre0,
               const unsigned short* __restrict__ pre1,
               const unsigned short* __restrict__ xsrc,
               const unsigned short* __restrict__ lrel,
               const unsigned short* __restrict__ B0,
               const unsigned short* __restrict__ B1,
               const unsigned short* __restrict__ B2,
               const float* __restrict__ bias,
               float* __restrict__ xo, unsigned short* __restrict__ xbo,
               int nrows)
{
  __shared__ __align__(16) unsigned short Bl[3 * PB_ * SB_];  // 111,360 B
  const int t   = threadIdx.x;
  const int bid = blockIdx.x;
  const int x8 = bid & 7, q = bid >> 3;
  const int part   = q % 3;
  const int rowblk = (q / 3) * 8 + x8;          // 0..255
  const int nth    = (part == 2) ? 3 : 5;
  const int ncol0  = part * PB_;
  const int nrB    = nth * 16;

  const unsigned short* Bs[3] = {B0, B1, B2};
  for (int task = t; task < 3 * nrB * 28; task += 512) {
    int seg = task / (nrB * 28);
    int rem = task % (nrB * 28);
    int n = rem / 28, c = rem % 28;
    uint4 v = *(const uint4*)(Bs[seg] + (size_t)(ncol0 + n) * WLD_ + c * 8);
    *(uint4*)(Bl + (size_t)(seg * PB_ + n) * SB_ + c * 8) = v;
  }
  __syncthreads();

  const int wave = t >> 6, lane = t & 63;
  const int m = lane & 15, quad = lane >> 4;

  uint4 lv[7];
  #pragma unroll
  for (int ks = 0; ks < 7; ks++)
    lv[ks] = *(const uint4*)(lrel + quad * 8 + ks * 32);

  if (part == 2)
    node_core<3>(Bl, pre0, pre1, xsrc, lv, bias, xo, xbo, rowblk, wave, m, quad, ncol0, nrows);
  else
    node_core<5>(Bl, pre0, pre1, xsrc, lv, bias, xo, xbo, rowblk, wave, m, quad, ncol0, nrows);
}

// ---------------------------------------------------------------------------
__global__ __launch_bounds__(256)
void gemm_rel200(const float* __restrict__ X, const unsigned short* __restrict__ Bp,
                 float* __restrict__ Out, int nrows)
{
  __shared__ __align__(16) unsigned short As[64 * LDA_];
  const int t  = threadIdx.x;
  const int r0 = blockIdx.x * 64;

  for (int task = t; task < 64 * 50; task += 256) {
    int i = task / 50, c = task % 50;
    int cr = min(r0 + i, nrows - 1);
    float4 xv = ((const float4*)(X + (size_t)cr * D_))[c];
    *(unsigned long long*)&As[i * LDA_ + c * 4] = pack4bf(xv.x, xv.y, xv.z, xv.w);
  }
  for (int task = t; task < 64 * 6; task += 256) {
    int i = task / 6, c = task % 6;
    *(unsigned long long*)&As[i * LDA_ + 200 + c * 4] = 0ull;
  }
  __syncthreads();

  const int wave = t >> 6, lane = t & 63;
  const int m = lane & 15, quad = lane >> 4;

  f32x4 acc[NT_];
  const f32x4 zero = {0.f, 0.f, 0.f, 0.f};
  #pragma unroll
  for (int i = 0; i < NT_; i++) acc[i] = zero;

  const unsigned short* arow = As + (wave * 16 + m) * LDA_ + quad * 8;
  const unsigned short* brow = Bp + (size_t)m * WLD_ + quad * 8;
  #pragma unroll
  for (int ks = 0; ks < 7; ks++) {
    bf16x8 av = *(const bf16x8*)(arow + ks * 32);
    #pragma unroll
    for (int tt = 0; tt < NT_; tt++) {
      bf16x8 bv = *(const bf16x8*)(brow + (size_t)tt * 16 * WLD_ + ks * 32);
      acc[tt] = __builtin_amdgcn_mfma_f32_16x16x32_bf16(av, bv, acc[tt], 0, 0, 0);
    }
  }

  #pragma unroll
  for (int rg = 0; rg < 4; rg++) {
    int row = r0 + wave * 16 + quad * 4 + rg;
    if (row < nrows) {
      #pragma unroll
      for (int tt = 0; tt < NT_; tt++) {
        int col = tt * 16 + m;
        if (col < D_) Out[(size_t)row * D_ + col] = acc[tt][rg];
      }
    }
  }
}

// ---------------------------------------------------------------------------
struct WP10 { const float* p[10]; };

__global__ void convert_weights(WP10 wp, unsigned short* __restrict__ wbp) {
  int i = blockIdx.x * 256 + threadIdx.x;
  if (i < 10 * 208 * WLD_) {
    int j = i / (208 * WLD_);
    int rem = i % (208 * WLD_);
    int n = rem / WLD_, k = rem % WLD_;
    float v = (n < D_ && k < D_) ? wp.p[j][(size_t)k * D_ + n] : 0.0f;  // Bp[n][k]=w[k][n]
    wbp[i] = (unsigned short)f2bf(v);
  }
}

__global__ void conv_f32_bf16_vec(const float* __restrict__ src,
                                  unsigned short* __restrict__ dst, int n4) {
  int i = blockIdx.x * 256 + threadIdx.x;
  if (i < n4) {
    float4 v = ((const float4*)src)[i];
    uint2 o;
    o.x = f2bf(v.x) | (f2bf(v.y) << 16);
    o.y = f2bf(v.z) | (f2bf(v.w) << 16);
    ((uint2*)dst)[i] = o;
  }
}

__global__ void build_rall(const float* __restrict__ rel_embs,
                           const float* __restrict__ loop_rel,
                           float* __restrict__ rall) {
  int i = blockIdx.x * 256 + threadIdx.x;
  if (i < 201 * D_) rall[i] = (i < 200 * D_) ? rel_embs[i] : loop_rel[i - 200 * D_];
}

__global__ void copy_row(const float* __restrict__ src, float* __restrict__ dst, int n) {
  int i = blockIdx.x * 256 + threadIdx.x;
  if (i < n) dst[i] = src[i];
}

__global__ void deg_count(const int* __restrict__ src, int* __restrict__ deg, int E) {
  int e = blockIdx.x * 256 + threadIdx.x;
  if (e < E) atomicAdd(&deg[src[e]], 1);
}

__global__ void norm_build(const int* __restrict__ src, const int* __restrict__ dst,
                           const int* __restrict__ deg, float* __restrict__ nrm, int E) {
  int e = blockIdx.x * 256 + threadIdx.x;
  if (e < E) {
    int a = deg[src[e]], b = deg[dst[e]];
    float fa = (a > 0) ? rsqrtf((float)a) : 0.0f;
    float fb = (b > 0) ? rsqrtf((float)b) : 0.0f;
    nrm[e] = fa * fb;
  }
}

// ---- exclusive scan (3 kernels) + CSR fill -------------------------------
constexpr int SCHUNK = 2048;

__global__ void scan_partial(const int* __restrict__ in, int* __restrict__ part, int n) {
  __shared__ int red[256];
  int b = blockIdx.x, t = threadIdx.x;
  int base = b * SCHUNK + t * 8;
  int s = 0;
  #pragma unroll
  for (int j = 0; j < 8; j++) { int i = base + j; if (i < n) s += in[i]; }
  red[t] = s; __syncthreads();
  for (int off = 128; off > 0; off >>= 1) {
    if (t < off) red[t] += red[t + off];
    __syncthreads();
  }
  if (t == 0) part[b] = red[0];
}

__global__ void scan_part_seq(int* part, int nb) {
  if (threadIdx.x == 0 && blockIdx.x == 0) {
    int run = 0;
    for (int i = 0; i < nb; i++) { int v = part[i]; part[i] = run; run += v; }
  }
}

__global__ void scan_final(const int* __restrict__ in, const int* __restrict__ part,
                           int* __restrict__ outs, int* __restrict__ cursor,
                           int n, int total) {
  __shared__ int buf[256];
  int b = blockIdx.x, t = threadIdx.x;
  int base = b * SCHUNK + t * 8;
  int v[8]; int s = 0;
  #pragma unroll
  for (int j = 0; j < 8; j++) { int i = base + j; v[j] = (i < n) ? in[i] : 0; s += v[j]; }
  buf[t] = s; __syncthreads();
  for (int off = 1; off < 256; off <<= 1) {
    int add = (t >= off) ? buf[t - off] : 0;
    __syncthreads();
    buf[t] += add;
    __syncthreads();
  }
  int excl = buf[t] - s + part[b];
  #pragma unroll
  for (int j = 0; j < 8; j++) {
    int i = base + j;
    if (i < n) { outs[i] = excl; cursor[i] = excl; }
    excl += v[j];
  }
  if (b == 0 && t == 0) outs[n] = total;
}

__global__ void fill_csr(const int* __restrict__ dstv, int* __restrict__ cursor,
                         int* __restrict__ csr, int E) {
  int e = blockIdx.x * 256 + threadIdx.x;
  if (e < E) {
    int pos = atomicAdd(&cursor[dstv[e]], 1);
    csr[pos] = e;
  }
}

// ---- covered-edge compaction ---------------------------------------------
__global__ void mk_flag(const int* __restrict__ deg, int* __restrict__ flag, int n) {
  int i = blockIdx.x * 256 + threadIdx.x;
  if (i < n) flag[i] = (deg[i] > 0) ? 1 : 0;
}

__global__ void fill_cov(const int* __restrict__ flag, const int* __restrict__ covstarts,
                         int* __restrict__ covlist, int* __restrict__ qidx, int n) {
  int e = blockIdx.x * 256 + threadIdx.x;
  if (e < n) {
    if (flag[e]) { int p = covstarts[e]; covlist[p] = e; qidx[e] = p; }
    else qidx[e] = -1;
  }
}

__global__ void finalize_cov(const int* __restrict__ covstarts, const int* __restrict__ flag,
                             int* __restrict__ ncovp) {
  if (threadIdx.x == 0 && blockIdx.x == 0)
    ncovp[0] = covstarts[E_DIR_ - 1] + flag[E_DIR_ - 1];
}

__global__ void gather_out(const float* __restrict__ x2, const float* __restrict__ r2,
                           const int* __restrict__ ent_ix, const int* __restrict__ rel_ix,
                           const int* __restrict__ quals_ix, float* __restrict__ out) {
  int i = blockIdx.x * 256 + threadIdx.x;
  if (i >= B_ * 14 * 50) return;
  int b = i / 700, rem = i % 700, slot = rem / 50, c = rem % 50;
  const float* srcrow; float* dstrow;
  if (slot == 0)      { srcrow = x2 + (size_t)ent_ix[b] * D_;  dstrow = out + OFS_SUB + (size_t)b * D_; }
  else if (slot == 1) { srcrow = r2 + (size_t)rel_ix[b] * D_;  dstrow = out + OFS_REL + (size_t)b * D_; }
  else if (slot < 8)  { int j = slot - 2;
                        srcrow = x2 + (size_t)quals_ix[b * 12 + 2 * j + 1] * D_;
                        dstrow = out + OFS_QOBJ + ((size_t)b * 6 + j) * D_; }
  else                { int j = slot - 8;
                        srcrow = r2 + (size_t)quals_ix[b * 12 + 2 * j] * D_;
                        dstrow = out + OFS_QREL + ((size_t)b * 6 + j) * D_; }
  ((float4*)dstrow)[c] = ((const float4*)srcrow)[c];
}

// ---------------------------------------------------------------------------
extern "C" void kernel_launch(void* const* d_in, const int* in_sizes, int n_in,
                              void* d_out, int out_size, void* d_ws, size_t ws_size,
                              hipStream_t stream)
{
  const float* ent       = (const float*)d_in[0];
  const float* rel_embs  = (const float*)d_in[1];
  const float* loop_rel1 = (const float*)d_in[12];
  const float* loop_rel2 = (const float*)d_in[13];
  const float* b1        = (const float*)d_in[14];
  const float* b2        = (const float*)d_in[15];
  const int*   ei        = (const int*)d_in[16];
  const int*   etype     = (const int*)d_in[17];
  const int*   quals     = (const int*)d_in[18];
  const int*   ent_ix    = (const int*)d_in[19];
  const int*   rel_ix    = (const int*)d_in[20];
  const int*   quals_ix  = (const int*)d_in[21];

  char* wsb = (char*)d_ws;
  size_t off = 0;
  auto walloc = [&](size_t bytes) -> char* {
    char* p = wsb + off; off += (bytes + 511) & ~(size_t)511; return p;
  };
  unsigned short* pre0  = (unsigned short*)walloc((size_t)N_ENT * D_ * 2);   // 80 MB
  unsigned short* pre1  = (unsigned short*)walloc((size_t)N_ENT * D_ * 2);   // 80 MB
  unsigned short* x_bf  = (unsigned short*)walloc((size_t)N_ENT * D_ * 2);   // 80 MB
  unsigned short* xb2   = (unsigned short*)walloc((size_t)N_ENT * D_ * 2);   // 80 MB (ping-pong)
  unsigned short* yq    = (unsigned short*)walloc((size_t)NQ_ * D_ * 2);     // 160 MB (compact y)
  float* norm1 = (float*)walloc((size_t)E_DIR_ * 4);
  float* norm2 = (float*)walloc((size_t)E_DIR_ * 4);
  int*   degA  = (int*)walloc((size_t)N_ENT * 4);
  int*   degB  = (int*)walloc((size_t)N_ENT * 4);
  int*   starts0 = (int*)walloc((size_t)(N_ENT + 1) * 4);
  int*   starts1 = (int*)walloc((size_t)(N_ENT + 1) * 4);
  int*   cursor0 = (int*)walloc((size_t)N_ENT * 4);
  int*   cursor1 = (int*)walloc((size_t)N_ENT * 4);
  int*   csr0    = (int*)walloc((size_t)E_DIR_ * 4);
  int*   csr1    = (int*)walloc((size_t)E_DIR_ * 4);
  int*   part    = (int*)walloc((size_t)256 * 4);
  // qual-CSR + coverage (per direction)
  int*   qstarts0 = (int*)walloc((size_t)(E_DIR_ + 1) * 4);
  int*   qstarts1 = (int*)walloc((size_t)(E_DIR_ + 1) * 4);
  int*   qcsr0    = (int*)walloc((size_t)NQ_ * 4);
  int*   qcsr1    = (int*)walloc((size_t)NQ_ * 4);
  int*   covlist0 = (int*)walloc((size_t)E_DIR_ * 4);
  int*   covlist1 = (int*)walloc((size_t)E_DIR_ * 4);
  int*   qidx0    = (int*)walloc((size_t)E_DIR_ * 4);
  int*   qidx1    = (int*)walloc((size_t)E_DIR_ * 4);
  int*   ncov0p   = (int*)walloc(64);
  int*   ncov1p   = (int*)walloc(64);
  // scratch (shared across dirs)
  int*   qdegS    = (int*)walloc((size_t)E_DIR_ * 4);
  int*   flagS    = (int*)walloc((size_t)E_DIR_ * 4);
  int*   qcurS    = (int*)walloc((size_t)E_DIR_ * 4);
  int*   covstS   = (int*)walloc((size_t)(E_DIR_ + 1) * 4);
  float* rall1 = (float*)walloc((size_t)201 * D_ * 4);
  float* rall2 = (float*)walloc((size_t)201 * D_ * 4);
  unsigned short* rall1_bf = (unsigned short*)walloc((size_t)201 * D_ * 2);
  unsigned short* rall2_bf = (unsigned short*)walloc((size_t)201 * D_ * 2);
  unsigned short* lrel1_bf = (unsigned short*)walloc((size_t)D_ * 2);
  unsigned short* lrel2_bf = (unsigned short*)walloc((size_t)D_ * 2);
  unsigned short* wbp = (unsigned short*)walloc((size_t)10 * 208 * WLD_ * 2);
  if (off > ws_size) fprintf(stderr, "ws overflow: need %zu have %zu\n", off, ws_size);

  float* out   = (float*)d_out;
  float* x_out = out + OFS_X;
  float* r_out = out + OFS_R;

  auto WB = [&](int j) { return wbp + (size_t)j * 208 * WLD_; };

  WP10 wp; for (int j = 0; j < 10; j++) wp.p[j] = (const float*)d_in[2 + j];
  convert_weights<<<(10 * 208 * WLD_ + 255) / 256, 256, 0, stream>>>(wp, wbp);
  build_rall<<<(201 * D_ + 255) / 256, 256, 0, stream>>>(rel_embs, loop_rel1, rall1);
  conv_f32_bf16_vec<<<(201 * 50 + 255) / 256, 256, 0, stream>>>(rall1, rall1_bf, 201 * 50);
  conv_f32_bf16_vec<<<(N_ENT * 50 + 255) / 256, 256, 0, stream>>>(ent, x_bf, N_ENT * 50);
  conv_f32_bf16_vec<<<1, 256, 0, stream>>>(loop_rel1, lrel1_bf, 50);
  conv_f32_bf16_vec<<<1, 256, 0, stream>>>(loop_rel2, lrel2_bf, 50);

  const int* src1 = ei;                // dir0 src = orig src
  const int* dst1 = ei + 2 * E_DIR_;   // dir0 dst = orig dst
  const int* src2 = ei + E_DIR_;       // dir1 src = orig dst
  const int* dst2 = ei + 3 * E_DIR_;   // dir1 dst = orig src

  int gE = (E_DIR_ + 255) / 256;
  hipMemsetAsync(degA, 0, (size_t)N_ENT * 4, stream);
  hipMemsetAsync(degB, 0, (size_t)N_ENT * 4, stream);
  deg_count<<<gE, 256, 0, stream>>>(src1, degA, E_DIR_);
  deg_count<<<gE, 256, 0, stream>>>(src2, degB, E_DIR_);
  norm_build<<<gE, 256, 0, stream>>>(src1, dst1, degA, norm1, E_DIR_);
  norm_build<<<gE, 256, 0, stream>>>(src2, dst2, degB, norm2, E_DIR_);

  // node CSR by dst
  int nbScan = (N_ENT + SCHUNK - 1) / SCHUNK;
  scan_partial<<<nbScan, 256, 0, stream>>>(degB, part, N_ENT);
  scan_part_seq<<<1, 64, 0, stream>>>(part, nbScan);
  scan_final<<<nbScan, 256, 0, stream>>>(degB, part, starts0, cursor0, N_ENT, E_DIR_);
  fill_csr<<<gE, 256, 0, stream>>>(dst1, cursor0, csr0, E_DIR_);

  scan_partial<<<nbScan, 256, 0, stream>>>(degA, part, N_ENT);
  scan_part_seq<<<1, 64, 0, stream>>>(part, nbScan);
  scan_final<<<nbScan, 256, 0, stream>>>(degA, part, starts1, cursor1, N_ENT, E_DIR_);
  fill_csr<<<gE, 256, 0, stream>>>(dst2, cursor1, csr1, E_DIR_);

  const int* q_r   = quals;
  const int* q_e   = quals + 2 * NQ_;
  const int* q_eid = quals + 4 * NQ_;

  // qual-CSR + covered-edge compaction, per direction
  int gNQ = (NQ_ + 255) / 256;
  int nbE = (E_DIR_ + SCHUNK - 1) / SCHUNK;
  for (int dir = 0; dir < 2; dir++) {
    const int* qid = q_eid + dir * NQ_;
    int* qst = dir ? qstarts1 : qstarts0;
    int* qcs = dir ? qcsr1 : qcsr0;
    int* cvl = dir ? covlist1 : covlist0;
    int* qix = dir ? qidx1 : qidx0;
    int* ncv = dir ? ncov1p : ncov0p;

    hipMemsetAsync(qdegS, 0, (size_t)E_DIR_ * 4, stream);
    deg_count<<<gNQ, 256, 0, stream>>>(qid, qdegS, NQ_);
    scan_partial<<<nbE, 256, 0, stream>>>(qdegS, part, E_DIR_);
    scan_part_seq<<<1, 64, 0, stream>>>(part, nbE);
    scan_final<<<nbE, 256, 0, stream>>>(qdegS, part, qst, qcurS, E_DIR_, NQ_);
    fill_csr<<<gNQ, 256, 0, stream>>>(qid, qcurS, qcs, NQ_);

    mk_flag<<<gE, 256, 0, stream>>>(qdegS, flagS, E_DIR_);
    scan_partial<<<nbE, 256, 0, stream>>>(flagS, part, E_DIR_);
    scan_part_seq<<<1, 64, 0, stream>>>(part, nbE);
    scan_final<<<nbE, 256, 0, stream>>>(flagS, part, covstS, qcurS, E_DIR_, 0);
    fill_cov<<<gE, 256, 0, stream>>>(flagS, covstS, cvl, qix, E_DIR_);
    finalize_cov<<<1, 64, 0, stream>>>(covstS, flagS, ncv);
  }

  for (int layer = 0; layer < 2; layer++) {
    const float* rallf = layer ? rall2 : rall1;
    const unsigned short* rallbf = layer ? rall2_bf : rall1_bf;
    const unsigned short* lrelbf = layer ? lrel2_bf : lrel1_bf;
    const float* bias = layer ? b2 : b1;
    const unsigned short* w_q    = WB(layer ? 9 : 4);
    const unsigned short* w_loop = WB(layer ? 7 : 2);
    const unsigned short* w_rel  = WB(layer ? 8 : 3);
    const unsigned short* w_in   = WB(layer ? 5 : 0);
    const unsigned short* w_out  = WB(layer ? 6 : 1);
    const unsigned short* xin    = layer ? xb2 : x_bf;   // ping-pong

    float* r_dst = layer ? r_out : rall2;
    gemm_rel200<<<4, 256, 0, stream>>>(rallf, w_rel, r_dst, 200);
    if (layer == 0) {
      copy_row<<<1, 256, 0, stream>>>(loop_rel2, rall2 + (size_t)200 * D_, D_);
      conv_f32_bf16_vec<<<(201 * 50 + 255) / 256, 256, 0, stream>>>(rall2, rall2_bf, 201 * 50);
    }

    for (int dir = 0; dir < 2; dir++) {
      const int* et  = etype + dir * E_DIR_;
      const int* qe  = q_e + dir * NQ_;
      const int* qr  = q_r + dir * NQ_;
      const int* s   = dir ? src2 : src1;
      const float* nm = dir ? norm2 : norm1;
      const int* sts = dir ? starts1 : starts0;
      const int* csr = dir ? csr1 : csr0;
      const int* qst = dir ? qstarts1 : qstarts0;
      const int* qcs = dir ? qcsr1 : qcsr0;
      const int* cvl = dir ? covlist1 : covlist0;
      const int* qix = dir ? qidx1 : qidx0;
      const int* ncv = dir ? ncov1p : ncov0p;
      unsigned short* pre = dir ? pre1 : pre0;

      gemm_qedge<<<(NQ_ + 63) / 64, 256, 0, stream>>>(xin, rallbf, qe, qr,
                                                      qst, qcs, cvl, ncv, w_q, yq);
      node_gather<<<(N_ENT + 3) / 4, 256, 0, stream>>>(sts, csr, s, et, nm,
                                                       qix, yq, xin, rallbf, pre);
    }

    if (layer == 0)
      gemm_node<<<768, 512, 0, stream>>>(pre0, pre1, xin, lrelbf,
                                         w_in, w_out, w_loop, bias,
                                         (float*)nullptr, xb2, N_ENT);
    else
      gemm_node<<<768, 512, 0, stream>>>(pre0, pre1, xin, lrelbf,
                                         w_in, w_out, w_loop, bias,
                                         x_out, (unsigned short*)nullptr, N_ENT);
  }

  gather_out<<<(B_ * 14 * 50 + 255) / 256, 256, 0, stream>>>(
      x_out, r_out, ent_ix, rel_ix, quals_ix, out);
}